// Round 3
// baseline (308.013 us; speedup 1.0000x reference)
//
#include <hip/hip_runtime.h>
#include <hip/hip_bf16.h>

typedef __attribute__((ext_vector_type(8))) short short8;   // bf16x8 MFMA frag
typedef __attribute__((ext_vector_type(4))) float f32x4;

constexpr int N1 = 16384, N2 = 8192, N3 = 4096;
constexpr int WN = 36864;
constexpr float ISQ3 = 0.57735026918962576451f;

__device__ __forceinline__ unsigned short f2bf(float f) {
  unsigned u = __builtin_bit_cast(unsigned, f);
  u += 0x7fffu + ((u >> 16) & 1u);   // RNE
  return (unsigned short)(u >> 16);
}

#define MFMA(a, b, c) __builtin_amdgcn_mfma_f32_16x16x32_bf16((a), (b), (c), 0, 0, 0)

// ---------------- fused prep: permute W2 -> Bp | MLP -> H | b2-part -> out ----------------
// blocks [0,1152): permute; [1152,2176): mlp; [2176,2688): init_out
__global__ __launch_bounds__(256)
void k_prep(const float* __restrict__ wgt, const float* __restrict__ W0,
            const float* __restrict__ b0, const float* __restrict__ W1,
            const float* __restrict__ b1, const float* __restrict__ W2,
            const float* __restrict__ b2, const float* __restrict__ bias,
            const float* __restrict__ d1, const float* __restrict__ d2,
            float* __restrict__ H, unsigned short* __restrict__ Bp,
            float* __restrict__ out) {
  __shared__ float h0s[4][64];
  __shared__ float s1s[8][128];
  __shared__ float v1s[8][64][3];
  __shared__ float dts[8][64];
  __shared__ float s2s[8];
  __shared__ float v2s[8][3];

  const int bid = blockIdx.x;
  if (bid < 1152) {
    const int g = bid * 256 + threadIdx.x;
    const int lane = g & 63;
    const int nth = g >> 6;
    const int kh = nth & 1, nt = nth >> 1;
    const int n = nt * 16 + (lane & 15);
    const int k0 = kh * 32 + (lane >> 4) * 8;
    short8 v;
#pragma unroll
    for (int j = 0; j < 8; ++j) v[j] = (short)f2bf(W2[(size_t)(k0 + j) * WN + n]);
    *(short8*)(Bp + (size_t)g * 8) = v;
  } else if (bid < 2176) {
    const int r = threadIdx.x >> 6, j = threadIdx.x & 63;
    const int e = (bid - 1152) * 4 + r;
    float a = b0[j];
#pragma unroll
    for (int i = 0; i < 16; ++i) a = fmaf(wgt[e * 16 + i], W0[i * 64 + j], a);
    h0s[r][j] = fmaxf(a, 0.f);
    __syncthreads();
    float a1 = b1[j];
#pragma unroll
    for (int i = 0; i < 64; ++i) a1 = fmaf(h0s[r][i], W1[i * 64 + j], a1);
    H[e * 64 + j] = fmaxf(a1, 0.f);
  } else {
    const int e0 = (bid - 2176) * 8;
    for (int x = threadIdx.x; x < 8 * 320; x += 256) {
      int e = x / 320, c = x % 320;
      float v = d1[(size_t)(e0 + e) * 320 + c];
      if (c < 128) s1s[e][c] = v;
      else { int q = c - 128; v1s[e][q / 3][q % 3] = v; }
    }
    if (threadIdx.x < 32) {
      int e = threadIdx.x >> 2, c = threadIdx.x & 3;
      float v = d2[(size_t)(e0 + e) * 4 + c];
      if (c == 0) s2s[e] = v; else v2s[e][c - 1] = v;
    }
    __syncthreads();
    for (int x = threadIdx.x; x < 8 * 64; x += 256) {
      int e = x >> 6, u = x & 63;
      dts[e][u] = v1s[e][u][0] * v2s[e][0] + v1s[e][u][1] * v2s[e][1] + v1s[e][u][2] * v2s[e][2];
    }
    __syncthreads();
    for (int c = threadIdx.x; c < 320; c += 256) {
      if (c < 128) {
        const int w = c;
        float ta[8] = {0,0,0,0,0,0,0,0}, td[8] = {0,0,0,0,0,0,0,0};
        for (int u = 0; u < 128; ++u) {
          float bv = b2[u * 128 + w];
#pragma unroll
          for (int e = 0; e < 8; ++e) ta[e] = fmaf(s1s[e][u], bv, ta[e]);
        }
        for (int u = 0; u < 64; ++u) {
          float bv = b2[N1 + N2 + N3 + u * 128 + w];
#pragma unroll
          for (int e = 0; e < 8; ++e) td[e] = fmaf(dts[e][u], bv, td[e]);
        }
        const float bw = bias[w];
#pragma unroll
        for (int e = 0; e < 8; ++e)
          out[(size_t)(e0 + e) * 320 + c] = fmaf(s2s[e], ta[e], ISQ3 * td[e]) + bw;
      } else {
        const int q = c - 128, w = q / 3, i = q % 3;
        float tb[8] = {0,0,0,0,0,0,0,0}, tc[8] = {0,0,0,0,0,0,0,0};
        for (int u = 0; u < 128; ++u) {
          float bv = b2[N1 + u * 64 + w];
#pragma unroll
          for (int e = 0; e < 8; ++e) tb[e] = fmaf(s1s[e][u], bv, tb[e]);
        }
        for (int u = 0; u < 64; ++u) {
          float bv = b2[N1 + N2 + u * 64 + w];
#pragma unroll
          for (int e = 0; e < 8; ++e) tc[e] = fmaf(v1s[e][u][i], bv, tc[e]);
        }
#pragma unroll
        for (int e = 0; e < 8; ++e)
          out[(size_t)(e0 + e) * 320 + c] = tb[e] * v2s[e][i] + tc[e] * s2s[e];
      }
    }
  }
}

// ---------------- main: H @ W2 (MFMA bf16) + u-reduction -> f32 partials (no atomics) ----------------
// grid = 128 e-tiles (32 rows) x SPLIT u-splits; 4 waves/WG; uq == blockIdx%SPLIT -> XCD-local L2 slice
template <int SPLIT>
__global__ __launch_bounds__(256, 4)
void k_main(const float* __restrict__ d1, const float* __restrict__ d2,
            const float* __restrict__ H, const unsigned short* __restrict__ Bp,
            float* __restrict__ P, float* __restrict__ out) {
  constexpr int U1 = 128 / SPLIT;   // a/b u-range per block
  constexpr int U2 = 64 / SPLIT;    // c/d u-range per block
  const int et = blockIdx.x / SPLIT;
  const int uq = blockIdx.x % SPLIT;
  const int e0 = et * 32;
  const int tid = threadIdx.x;
  const int wid = tid >> 6, lane = tid & 63;
  const int nl = lane & 15, grp = lane >> 4;

  __shared__ __align__(16) float s1T[U1][36];
  __shared__ __align__(16) float v1T[U2][3][36];
  __shared__ __align__(16) float dtT[U2][36];
  __shared__ float s2s[32];
  __shared__ float v2s[32][3];

  for (int x = tid; x < 32 * U1; x += 256) {
    int e = x / U1, ul = x % U1;
    s1T[ul][e] = d1[(size_t)(e0 + e) * 320 + uq * U1 + ul];
  }
  for (int x = tid; x < 32 * 3 * U2; x += 256) {
    int e = x / (3 * U2), q = x % (3 * U2);
    v1T[q / 3][q % 3][e] = d1[(size_t)(e0 + e) * 320 + 128 + uq * 3 * U2 + q];
  }
  if (tid < 128) {
    int e = tid >> 2, c = tid & 3;
    float v = d2[(size_t)(e0 + e) * 4 + c];
    if (c == 0) s2s[e] = v; else v2s[e][c - 1] = v;
  }
  __syncthreads();
  for (int x = tid; x < U2 * 32; x += 256) {
    int ul = x >> 5, e = x & 31;
    dtT[ul][e] = v1T[ul][0][e] * v2s[e][0] + v1T[ul][1][e] * v2s[e][1] + v1T[ul][2][e] * v2s[e][2];
  }

  // A-frags from H (register-resident)
  short8 hA00, hA01, hA10, hA11;
  {
    const float* hp0 = H + (size_t)(e0 + nl) * 64 + grp * 8;
    const float* hp1 = H + (size_t)(e0 + 16 + nl) * 64 + grp * 8;
    short8 v;
#pragma unroll
    for (int j = 0; j < 8; ++j) v[j] = (short)f2bf(hp0[j]);      hA00 = v;
#pragma unroll
    for (int j = 0; j < 8; ++j) v[j] = (short)f2bf(hp0[32 + j]); hA01 = v;
#pragma unroll
    for (int j = 0; j < 8; ++j) v[j] = (short)f2bf(hp1[j]);      hA10 = v;
#pragma unroll
    for (int j = 0; j < 8; ++j) v[j] = (short)f2bf(hp1[32 + j]); hA11 = v;
  }
  __syncthreads();

  const short8* Bp8 = (const short8*)Bp;
  f32x4 accA[2][2] = {};
  f32x4 accB[2] = {};

  // blocks a (nt = (uq*U1+ul)*8 + 2*wid + wl) and b (nt = 1024 + (uq*U1+ul)*4 + wid)
  {
    const short8* pa = Bp8 + (size_t)(uq * U1 * 8 + 2 * wid) * 128 + lane;
    const short8* pb = Bp8 + (size_t)(1024 + uq * U1 * 4 + wid) * 128 + lane;
    short8 n0 = pa[0], n1 = pa[64], n2 = pa[128], n3 = pa[192], n4 = pb[0], n5 = pb[64];
#pragma unroll 4
    for (int ul = 0; ul < U1; ++ul) {
      short8 c0 = n0, c1 = n1, c2 = n2, c3 = n3, c4 = n4, c5 = n5;
      if (ul < U1 - 1) {
        pa += 1024; pb += 512;
        n0 = pa[0]; n1 = pa[64]; n2 = pa[128]; n3 = pa[192]; n4 = pb[0]; n5 = pb[64];
      }
      f32x4 s10 = *(const f32x4*)&s1T[ul][grp * 4];
      f32x4 s11 = *(const f32x4*)&s1T[ul][16 + grp * 4];
      f32x4 t0 = {0.f,0.f,0.f,0.f};
      t0 = MFMA(hA00, c0, t0); t0 = MFMA(hA01, c1, t0); accA[0][0] += s10 * t0;
      f32x4 t1 = {0.f,0.f,0.f,0.f};
      t1 = MFMA(hA10, c0, t1); t1 = MFMA(hA11, c1, t1); accA[1][0] += s11 * t1;
      f32x4 t2 = {0.f,0.f,0.f,0.f};
      t2 = MFMA(hA00, c2, t2); t2 = MFMA(hA01, c3, t2); accA[0][1] += s10 * t2;
      f32x4 t3 = {0.f,0.f,0.f,0.f};
      t3 = MFMA(hA10, c2, t3); t3 = MFMA(hA11, c3, t3); accA[1][1] += s11 * t3;
      f32x4 t4 = {0.f,0.f,0.f,0.f};
      t4 = MFMA(hA00, c4, t4); t4 = MFMA(hA01, c5, t4); accB[0] += s10 * t4;
      f32x4 t5 = {0.f,0.f,0.f,0.f};
      t5 = MFMA(hA10, c4, t5); t5 = MFMA(hA11, c5, t5); accB[1] += s11 * t5;
    }
  }

  f32x4 accC[2][3] = {};
  f32x4 accD[2][2] = {};

  // blocks d (nt = 1792 + (uq*U2+ul)*8 + 2*wid + wl) and c (nt = 1536 + (uq*U2+ul)*4 + wid)
  {
    const short8* pd = Bp8 + (size_t)(1792 + uq * U2 * 8 + 2 * wid) * 128 + lane;
    const short8* pc = Bp8 + (size_t)(1536 + uq * U2 * 4 + wid) * 128 + lane;
    short8 n0 = pd[0], n1 = pd[64], n2 = pd[128], n3 = pd[192], n4 = pc[0], n5 = pc[64];
#pragma unroll 4
    for (int ul = 0; ul < U2; ++ul) {
      short8 c0 = n0, c1 = n1, c2 = n2, c3 = n3, c4 = n4, c5 = n5;
      if (ul < U2 - 1) {
        pd += 1024; pc += 512;
        n0 = pd[0]; n1 = pd[64]; n2 = pd[128]; n3 = pd[192]; n4 = pc[0]; n5 = pc[64];
      }
      f32x4 dv0 = *(const f32x4*)&dtT[ul][grp * 4];
      f32x4 dv1 = *(const f32x4*)&dtT[ul][16 + grp * 4];
      f32x4 t0 = {0.f,0.f,0.f,0.f};
      t0 = MFMA(hA00, c0, t0); t0 = MFMA(hA01, c1, t0); accD[0][0] += dv0 * t0;
      f32x4 t1 = {0.f,0.f,0.f,0.f};
      t1 = MFMA(hA10, c0, t1); t1 = MFMA(hA11, c1, t1); accD[1][0] += dv1 * t1;
      f32x4 t2 = {0.f,0.f,0.f,0.f};
      t2 = MFMA(hA00, c2, t2); t2 = MFMA(hA01, c3, t2); accD[0][1] += dv0 * t2;
      f32x4 t3 = {0.f,0.f,0.f,0.f};
      t3 = MFMA(hA10, c2, t3); t3 = MFMA(hA11, c3, t3); accD[1][1] += dv1 * t3;
      f32x4 t4 = {0.f,0.f,0.f,0.f};
      t4 = MFMA(hA00, c4, t4); t4 = MFMA(hA01, c5, t4);
      accC[0][0] += (*(const f32x4*)&v1T[ul][0][grp * 4]) * t4;
      accC[0][1] += (*(const f32x4*)&v1T[ul][1][grp * 4]) * t4;
      accC[0][2] += (*(const f32x4*)&v1T[ul][2][grp * 4]) * t4;
      f32x4 t5 = {0.f,0.f,0.f,0.f};
      t5 = MFMA(hA10, c4, t5); t5 = MFMA(hA11, c5, t5);
      accC[1][0] += (*(const f32x4*)&v1T[ul][0][16 + grp * 4]) * t5;
      accC[1][1] += (*(const f32x4*)&v1T[ul][1][16 + grp * 4]) * t5;
      accC[1][2] += (*(const f32x4*)&v1T[ul][2][16 + grp * 4]) * t5;
    }
  }

  // epilogue: plain stores (partials to P, or direct += into out when SPLIT==1)
#pragma unroll
  for (int m = 0; m < 2; ++m) {
#pragma unroll
    for (int r = 0; r < 4; ++r) {
      const int el = m * 16 + grp * 4 + r;
      const float s2v = s2s[el];
      const float v0a = s2v * accA[m][0][r] + ISQ3 * accD[m][0][r];
      const float v0b = s2v * accA[m][1][r] + ISQ3 * accD[m][1][r];
      const int wa = (2 * wid) * 16 + nl, wb = (2 * wid + 1) * 16 + nl;
      const int w1 = wid * 16 + nl;
      if constexpr (SPLIT == 1) {
        float* orow = out + (size_t)(e0 + el) * 320;
        orow[wa] += v0a;
        orow[wb] += v0b;
#pragma unroll
        for (int i = 0; i < 3; ++i)
          orow[128 + 3 * w1 + i] += accB[m][r] * v2s[el][i] + accC[m][i][r] * s2v;
      } else {
        float* prow = P + ((size_t)(et * SPLIT + uq) * 32 + el) * 320;
        prow[wa] = v0a;
        prow[wb] = v0b;
#pragma unroll
        for (int i = 0; i < 3; ++i)
          prow[128 + 3 * w1 + i] = accB[m][r] * v2s[el][i] + accC[m][i][r] * s2v;
      }
    }
  }
}

// ---------------- reduce: out += sum_s P[et,s,:,:]  (one owner per element, no atomics) ----------------
template <int SPLIT>
__global__ __launch_bounds__(256)
void k_reduce(const float* __restrict__ P, float* __restrict__ out) {
  const int idx4 = blockIdx.x * 256 + threadIdx.x;   // one float4 per thread; 327680 total
  const int e = idx4 / 80;
  const int c4 = idx4 % 80;
  const int et = e >> 5, el = e & 31;
  const f32x4* Pb = (const f32x4*)P + ((size_t)(et * SPLIT) * 32 + el) * 80 + c4;
  f32x4 s = *((f32x4*)out + (size_t)e * 80 + c4);
#pragma unroll
  for (int q = 0; q < SPLIT; ++q) s += Pb[(size_t)q * 2560];
  *((f32x4*)out + (size_t)e * 80 + c4) = s;
}

extern "C" void kernel_launch(void* const* d_in, const int* in_sizes, int n_in,
                              void* d_out, int out_size, void* d_ws, size_t ws_size,
                              hipStream_t stream) {
  const float* d1   = (const float*)d_in[0];
  const float* d2   = (const float*)d_in[1];
  const float* wgt  = (const float*)d_in[2];
  const float* W0   = (const float*)d_in[3];
  const float* b0   = (const float*)d_in[4];
  const float* W1   = (const float*)d_in[5];
  const float* b1   = (const float*)d_in[6];
  const float* W2   = (const float*)d_in[7];
  const float* b2   = (const float*)d_in[8];
  const float* bias = (const float*)d_in[9];
  float* out = (float*)d_out;

  float* H = (float*)d_ws;                                                      // [0, 1 MiB)
  unsigned short* Bp = (unsigned short*)((char*)d_ws + (size_t)(1 << 20));      // [1 MiB, ~5.72 MiB)
  float* P = (float*)((char*)d_ws + (size_t)(8 << 20));                         // partials

  const size_t pre = (size_t)(8 << 20);
  const size_t per_split = (size_t)4096 * 320 * 4;   // 5.24 MB per split level

  k_prep<<<2688, 256, 0, stream>>>(wgt, W0, b0, W1, b1, W2, b2, bias, d1, d2, H, Bp, out);

  if (ws_size >= pre + 8 * per_split) {
    k_main<8><<<1024, 256, 0, stream>>>(d1, d2, H, Bp, P, out);
    k_reduce<8><<<1280, 256, 0, stream>>>(P, out);
  } else if (ws_size >= pre + 4 * per_split) {
    k_main<4><<<512, 256, 0, stream>>>(d1, d2, H, Bp, P, out);
    k_reduce<4><<<1280, 256, 0, stream>>>(P, out);
  } else if (ws_size >= pre + 2 * per_split) {
    k_main<2><<<256, 256, 0, stream>>>(d1, d2, H, Bp, P, out);
    k_reduce<2><<<1280, 256, 0, stream>>>(P, out);
  } else {
    k_main<1><<<128, 256, 0, stream>>>(d1, d2, H, Bp, P, out);
  }
}

// Round 4
// 93.090 us; speedup vs baseline: 3.3088x; 3.3088x over previous
//
#include <hip/hip_runtime.h>
#include <hip/hip_bf16.h>

typedef __attribute__((ext_vector_type(8))) short short8;   // bf16x8 MFMA frag
typedef __attribute__((ext_vector_type(4))) float f32x4;

constexpr int N1 = 16384, N2 = 8192, N3 = 4096;
constexpr int WN = 36864;
constexpr float ISQ3 = 0.57735026918962576451f;

__device__ __forceinline__ unsigned short f2bf(float f) {
  unsigned u = __builtin_bit_cast(unsigned, f);
  u += 0x7fffu + ((u >> 16) & 1u);   // RNE
  return (unsigned short)(u >> 16);
}

#define MFMA(a, b, c) __builtin_amdgcn_mfma_f32_16x16x32_bf16((a), (b), (c), 0, 0, 0)

// ---------------- prep1: permute W2->Bp | MLP->H | b2-part->out | d1->d1T | d2->d2T ----------------
// bid [0,1152): permute; [1152,2176): mlp; [2176,2688): init_out; [2688,3968): d1T; [3968,3984): d2T
__global__ __launch_bounds__(256)
void k_prep1(const float* __restrict__ wgt, const float* __restrict__ W0,
             const float* __restrict__ b0, const float* __restrict__ W1,
             const float* __restrict__ b1, const float* __restrict__ W2,
             const float* __restrict__ b2, const float* __restrict__ bias,
             const float* __restrict__ d1, const float* __restrict__ d2,
             float* __restrict__ H, unsigned short* __restrict__ Bp,
             float* __restrict__ d1T, float* __restrict__ d2T,
             float* __restrict__ out) {
  __shared__ float h0s[4][64];
  __shared__ float s1s[8][128];
  __shared__ float v1s[8][64][3];
  __shared__ float dts[8][64];
  __shared__ float s2s[8];
  __shared__ float v2s[8][3];
  __shared__ float tile[32][33];

  const int bid = blockIdx.x;
  if (bid < 1152) {
    const int g = bid * 256 + threadIdx.x;
    const int lane = g & 63;
    const int nth = g >> 6;
    const int kh = nth & 1, nt = nth >> 1;
    const int n = nt * 16 + (lane & 15);
    const int k0 = kh * 32 + (lane >> 4) * 8;
    short8 v;
#pragma unroll
    for (int j = 0; j < 8; ++j) v[j] = (short)f2bf(W2[(size_t)(k0 + j) * WN + n]);
    *(short8*)(Bp + (size_t)g * 8) = v;
  } else if (bid < 2176) {
    const int r = threadIdx.x >> 6, j = threadIdx.x & 63;
    const int e = (bid - 1152) * 4 + r;
    float a = b0[j];
#pragma unroll
    for (int i = 0; i < 16; ++i) a = fmaf(wgt[e * 16 + i], W0[i * 64 + j], a);
    h0s[r][j] = fmaxf(a, 0.f);
    __syncthreads();
    float a1 = b1[j];
#pragma unroll
    for (int i = 0; i < 64; ++i) a1 = fmaf(h0s[r][i], W1[i * 64 + j], a1);
    H[e * 64 + j] = fmaxf(a1, 0.f);
  } else if (bid < 2688) {
    const int e0 = (bid - 2176) * 8;
    for (int x = threadIdx.x; x < 8 * 320; x += 256) {
      int e = x / 320, c = x % 320;
      float v = d1[(size_t)(e0 + e) * 320 + c];
      if (c < 128) s1s[e][c] = v;
      else { int q = c - 128; v1s[e][q / 3][q % 3] = v; }
    }
    if (threadIdx.x < 32) {
      int e = threadIdx.x >> 2, c = threadIdx.x & 3;
      float v = d2[(size_t)(e0 + e) * 4 + c];
      if (c == 0) s2s[e] = v; else v2s[e][c - 1] = v;
    }
    __syncthreads();
    for (int x = threadIdx.x; x < 8 * 64; x += 256) {
      int e = x >> 6, u = x & 63;
      dts[e][u] = v1s[e][u][0] * v2s[e][0] + v1s[e][u][1] * v2s[e][1] + v1s[e][u][2] * v2s[e][2];
    }
    __syncthreads();
    for (int c = threadIdx.x; c < 320; c += 256) {
      if (c < 128) {
        const int w = c;
        float ta[8] = {0,0,0,0,0,0,0,0}, td[8] = {0,0,0,0,0,0,0,0};
        for (int u = 0; u < 128; ++u) {
          float bv = b2[u * 128 + w];
#pragma unroll
          for (int e = 0; e < 8; ++e) ta[e] = fmaf(s1s[e][u], bv, ta[e]);
        }
        for (int u = 0; u < 64; ++u) {
          float bv = b2[N1 + N2 + N3 + u * 128 + w];
#pragma unroll
          for (int e = 0; e < 8; ++e) td[e] = fmaf(dts[e][u], bv, td[e]);
        }
        const float bw = bias[w];
#pragma unroll
        for (int e = 0; e < 8; ++e)
          out[(size_t)(e0 + e) * 320 + c] = fmaf(s2s[e], ta[e], ISQ3 * td[e]) + bw;
      } else {
        const int q = c - 128, w = q / 3, i = q % 3;
        float tb[8] = {0,0,0,0,0,0,0,0}, tc[8] = {0,0,0,0,0,0,0,0};
        for (int u = 0; u < 128; ++u) {
          float bv = b2[N1 + u * 64 + w];
#pragma unroll
          for (int e = 0; e < 8; ++e) tb[e] = fmaf(s1s[e][u], bv, tb[e]);
        }
        for (int u = 0; u < 64; ++u) {
          float bv = b2[N1 + N2 + u * 64 + w];
#pragma unroll
          for (int e = 0; e < 8; ++e) tc[e] = fmaf(v1s[e][u][i], bv, tc[e]);
        }
#pragma unroll
        for (int e = 0; e < 8; ++e)
          out[(size_t)(e0 + e) * 320 + c] = tb[e] * v2s[e][i] + tc[e] * s2s[e];
      }
    }
  } else if (bid < 3968) {
    // ---- d1 [4096][320] -> d1T [320][4096], 32x32 LDS tiles
    const int tb = bid - 2688;
    const int er = tb / 10, cr = tb % 10;
    const int tr = threadIdx.x >> 5, tc = threadIdx.x & 31;
#pragma unroll
    for (int k = 0; k < 4; ++k) {
      int row = tr + k * 8;
      tile[row][tc] = d1[(size_t)(er * 32 + row) * 320 + cr * 32 + tc];
    }
    __syncthreads();
#pragma unroll
    for (int k = 0; k < 4; ++k) {
      int row = tr + k * 8;
      d1T[(size_t)(cr * 32 + row) * 4096 + er * 32 + tc] = tile[tc][row];
    }
  } else {
    // ---- d2 [4096][4] -> d2T [4][4096]
    const int e = (bid - 3968) * 256 + threadIdx.x;
#pragma unroll
    for (int c = 0; c < 4; ++c) d2T[c * 4096 + e] = d2[(size_t)e * 4 + c];
  }
}

// ---------------- prep2: dtT[u][e] = sum_i d1T[128+3u+i][e] * d2T[1+i][e] ----------------
__global__ __launch_bounds__(256)
void k_prep2(const float* __restrict__ d1T, const float* __restrict__ d2T,
             float* __restrict__ dtT) {
  const int u = blockIdx.x >> 2, q = blockIdx.x & 3;
  const int e = q * 1024 + threadIdx.x * 4;
  f32x4 a0 = *(const f32x4*)(d1T + (size_t)(128 + 3 * u) * 4096 + e);
  f32x4 a1 = *(const f32x4*)(d1T + (size_t)(129 + 3 * u) * 4096 + e);
  f32x4 a2 = *(const f32x4*)(d1T + (size_t)(130 + 3 * u) * 4096 + e);
  f32x4 w0 = *(const f32x4*)(d2T + 4096 + e);
  f32x4 w1 = *(const f32x4*)(d2T + 8192 + e);
  f32x4 w2 = *(const f32x4*)(d2T + 12288 + e);
  *(f32x4*)(dtT + (size_t)u * 4096 + e) = a0 * w0 + a1 * w1 + a2 * w2;
}

// ---------------- main: column-group decomposition, no atomics, no partials ----------------
// 1536 blocks = 128 e-tiles x 12 col-groups (8 AD + 4 BC); 4 waves split u; LDS reduce; out +=
__global__ __launch_bounds__(256, 4)
void k_main(const float* __restrict__ d1T, const float* __restrict__ d2T,
            const float* __restrict__ dtT, const float* __restrict__ H,
            const unsigned short* __restrict__ Bp, float* __restrict__ out) {
  const int i = blockIdx.x;
  const int g8 = i & 7;
  const int jj = i >> 3;
  int g, et;
  if (jj < 128) { g = g8; et = jj; }
  else { g = 8 + (g8 & 3); et = ((jj - 128) << 1) + (g8 >> 2); }
  const int e0 = et * 32;
  const int tid = threadIdx.x;
  const int wid = tid >> 6, lane = tid & 63;
  const int nl = lane & 15, grp = lane >> 4;

  __shared__ float red[4][64][33];   // padded: +1 breaks the 32-stride bank alias

  // A-frags from H (register-resident)
  short8 hA00, hA01, hA10, hA11;
  {
    const float* hp0 = H + (size_t)(e0 + nl) * 64 + grp * 8;
    const float* hp1 = H + (size_t)(e0 + 16 + nl) * 64 + grp * 8;
    short8 v;
#pragma unroll
    for (int j = 0; j < 8; ++j) v[j] = (short)f2bf(hp0[j]);      hA00 = v;
#pragma unroll
    for (int j = 0; j < 8; ++j) v[j] = (short)f2bf(hp0[32 + j]); hA01 = v;
#pragma unroll
    for (int j = 0; j < 8; ++j) v[j] = (short)f2bf(hp1[j]);      hA10 = v;
#pragma unroll
    for (int j = 0; j < 8; ++j) v[j] = (short)f2bf(hp1[32 + j]); hA11 = v;
  }

  const short8* Bp8 = (const short8*)Bp;

  if (g < 8) {
    const int j = g;   // a-col / d-col / out0 w-tile
    f32x4 aA0 = {}, aA1 = {}, aD0 = {}, aD1 = {};
    {  // phase A: u = wid*32..+31, nt = u*8 + j
      size_t idx = ((size_t)(wid * 256 + j)) * 128 + lane;
      short8 n0 = Bp8[idx], n1 = Bp8[idx + 64];
      const float* sp = d1T + (size_t)(wid * 32) * 4096 + e0 + grp * 4;
#pragma unroll 4
      for (int ul = 0; ul < 32; ++ul) {
        short8 c0 = n0, c1 = n1;
        if (ul < 31) { idx += 1024; n0 = Bp8[idx]; n1 = Bp8[idx + 64]; }
        f32x4 s10 = *(const f32x4*)sp;
        f32x4 s11 = *(const f32x4*)(sp + 16);
        sp += 4096;
        f32x4 t0 = {0.f,0.f,0.f,0.f}; t0 = MFMA(hA00, c0, t0); t0 = MFMA(hA01, c1, t0); aA0 += s10 * t0;
        f32x4 t1 = {0.f,0.f,0.f,0.f}; t1 = MFMA(hA10, c0, t1); t1 = MFMA(hA11, c1, t1); aA1 += s11 * t1;
      }
    }
    {  // phase D: u = wid*16..+15, nt = 1792 + u*8 + j
      size_t idx = ((size_t)(1792 + wid * 128 + j)) * 128 + lane;
      short8 n0 = Bp8[idx], n1 = Bp8[idx + 64];
      const float* dp = dtT + (size_t)(wid * 16) * 4096 + e0 + grp * 4;
#pragma unroll 4
      for (int ul = 0; ul < 16; ++ul) {
        short8 c0 = n0, c1 = n1;
        if (ul < 15) { idx += 1024; n0 = Bp8[idx]; n1 = Bp8[idx + 64]; }
        f32x4 dv0 = *(const f32x4*)dp;
        f32x4 dv1 = *(const f32x4*)(dp + 16);
        dp += 4096;
        f32x4 t0 = {0.f,0.f,0.f,0.f}; t0 = MFMA(hA00, c0, t0); t0 = MFMA(hA01, c1, t0); aD0 += dv0 * t0;
        f32x4 t1 = {0.f,0.f,0.f,0.f}; t1 = MFMA(hA10, c0, t1); t1 = MFMA(hA11, c1, t1); aD1 += dv1 * t1;
      }
    }
#pragma unroll
    for (int r = 0; r < 4; ++r) {
      red[wid][lane][r]      = aA0[r];
      red[wid][lane][4 + r]  = aA1[r];
      red[wid][lane][8 + r]  = aD0[r];
      red[wid][lane][12 + r] = aD1[r];
    }
    __syncthreads();
    for (int oidx = tid; oidx < 512; oidx += 256) {
      const int e = oidx >> 4, w = oidx & 15;
      const int m = e >> 4, gr = (e >> 2) & 3, r = e & 3;
      const int ln = gr * 16 + w;
      float ta = 0.f, td = 0.f;
#pragma unroll
      for (int t = 0; t < 4; ++t) { ta += red[t][ln][m * 4 + r]; td += red[t][ln][8 + m * 4 + r]; }
      const float s2 = d2T[e0 + e];
      out[(size_t)(e0 + e) * 320 + j * 16 + w] += s2 * ta + ISQ3 * td;
    }
  } else {
    const int j = g - 8;   // b-col / c-col / out1 w1-tile
    f32x4 aB0 = {}, aB1 = {};
    f32x4 c00 = {}, c01 = {}, c02 = {}, c10 = {}, c11 = {}, c12 = {};
    {  // phase B: u = wid*32..+31, nt = 1024 + u*4 + j
      size_t idx = ((size_t)(1024 + wid * 128 + j)) * 128 + lane;
      short8 n0 = Bp8[idx], n1 = Bp8[idx + 64];
      const float* sp = d1T + (size_t)(wid * 32) * 4096 + e0 + grp * 4;
#pragma unroll 4
      for (int ul = 0; ul < 32; ++ul) {
        short8 c0 = n0, c1 = n1;
        if (ul < 31) { idx += 512; n0 = Bp8[idx]; n1 = Bp8[idx + 64]; }
        f32x4 s10 = *(const f32x4*)sp;
        f32x4 s11 = *(const f32x4*)(sp + 16);
        sp += 4096;
        f32x4 t0 = {0.f,0.f,0.f,0.f}; t0 = MFMA(hA00, c0, t0); t0 = MFMA(hA01, c1, t0); aB0 += s10 * t0;
        f32x4 t1 = {0.f,0.f,0.f,0.f}; t1 = MFMA(hA10, c0, t1); t1 = MFMA(hA11, c1, t1); aB1 += s11 * t1;
      }
    }
    {  // phase C: u = wid*16..+15, nt = 1536 + u*4 + j; v1 rows 128+3u+i
      size_t idx = ((size_t)(1536 + wid * 64 + j)) * 128 + lane;
      short8 n0 = Bp8[idx], n1 = Bp8[idx + 64];
      const float* vp = d1T + (size_t)(128 + 3 * (wid * 16)) * 4096 + e0 + grp * 4;
#pragma unroll 2
      for (int ul = 0; ul < 16; ++ul) {
        short8 c0 = n0, c1 = n1;
        if (ul < 15) { idx += 512; n0 = Bp8[idx]; n1 = Bp8[idx + 64]; }
        f32x4 t0 = {0.f,0.f,0.f,0.f}; t0 = MFMA(hA00, c0, t0); t0 = MFMA(hA01, c1, t0);
        f32x4 t1 = {0.f,0.f,0.f,0.f}; t1 = MFMA(hA10, c0, t1); t1 = MFMA(hA11, c1, t1);
        f32x4 v0a = *(const f32x4*)(vp);        f32x4 v0b = *(const f32x4*)(vp + 16);
        f32x4 v1a = *(const f32x4*)(vp + 4096); f32x4 v1b = *(const f32x4*)(vp + 4112);
        f32x4 v2a = *(const f32x4*)(vp + 8192); f32x4 v2b = *(const f32x4*)(vp + 8208);
        vp += 12288;
        c00 += v0a * t0; c01 += v1a * t0; c02 += v2a * t0;
        c10 += v0b * t1; c11 += v1b * t1; c12 += v2b * t1;
      }
    }
#pragma unroll
    for (int r = 0; r < 4; ++r) {
      red[wid][lane][r]      = aB0[r];
      red[wid][lane][4 + r]  = aB1[r];
      red[wid][lane][8 + r]  = c00[r];
      red[wid][lane][12 + r] = c01[r];
      red[wid][lane][16 + r] = c02[r];
      red[wid][lane][20 + r] = c10[r];
      red[wid][lane][24 + r] = c11[r];
      red[wid][lane][28 + r] = c12[r];
    }
    __syncthreads();
    for (int oidx = tid; oidx < 1536; oidx += 256) {
      const int e = oidx / 48, rem = oidx % 48;
      const int w = rem / 3, ii = rem % 3;
      const int m = e >> 4, gr = (e >> 2) & 3, r = e & 3;
      const int ln = gr * 16 + w;
      float tb = 0.f, tc = 0.f;
#pragma unroll
      for (int t = 0; t < 4; ++t) {
        tb += red[t][ln][m * 4 + r];
        tc += red[t][ln][8 + (m * 3 + ii) * 4 + r];
      }
      const float s2 = d2T[e0 + e];
      const float v2 = d2T[(1 + ii) * 4096 + e0 + e];
      out[(size_t)(e0 + e) * 320 + 128 + j * 48 + 3 * w + ii] += tb * v2 + tc * s2;
    }
  }
}

extern "C" void kernel_launch(void* const* d_in, const int* in_sizes, int n_in,
                              void* d_out, int out_size, void* d_ws, size_t ws_size,
                              hipStream_t stream) {
  const float* d1   = (const float*)d_in[0];
  const float* d2   = (const float*)d_in[1];
  const float* wgt  = (const float*)d_in[2];
  const float* W0   = (const float*)d_in[3];
  const float* b0   = (const float*)d_in[4];
  const float* W1   = (const float*)d_in[5];
  const float* b1   = (const float*)d_in[6];
  const float* W2   = (const float*)d_in[7];
  const float* b2   = (const float*)d_in[8];
  const float* bias = (const float*)d_in[9];
  float* out = (float*)d_out;

  char* ws = (char*)d_ws;
  float* H          = (float*)(ws);                         // 1 MiB
  unsigned short* Bp = (unsigned short*)(ws + (1u << 20));  // 4.72 MB
  float* d1T        = (float*)(ws + (8u << 20));            // 5.24 MB
  float* dtT        = (float*)(ws + (16u << 20));           // 1 MB
  float* d2T        = (float*)(ws + (20u << 20));           // 64 KB

  k_prep1<<<3984, 256, 0, stream>>>(wgt, W0, b0, W1, b1, W2, b2, bias, d1, d2,
                                    H, Bp, d1T, d2T, out);
  k_prep2<<<256, 256, 0, stream>>>(d1T, d2T, dtT);
  k_main<<<1536, 256, 0, stream>>>(d1T, d2T, dtT, H, Bp, out);
}

// Round 5
// 82.145 us; speedup vs baseline: 3.7496x; 1.1332x over previous
//
#include <hip/hip_runtime.h>
#include <hip/hip_bf16.h>

typedef __attribute__((ext_vector_type(8))) short short8;   // bf16x8 MFMA frag
typedef __attribute__((ext_vector_type(4))) float f32x4;

constexpr int N1 = 16384, N2 = 8192, N3 = 4096;
constexpr int WN = 36864;
constexpr float ISQ3 = 0.57735026918962576451f;

__device__ __forceinline__ unsigned short f2bf(float f) {
  unsigned u = __builtin_bit_cast(unsigned, f);
  u += 0x7fffu + ((u >> 16) & 1u);   // RNE
  return (unsigned short)(u >> 16);
}

#define MFMA(a, b, c) __builtin_amdgcn_mfma_f32_16x16x32_bf16((a), (b), (c), 0, 0, 0)

// ---------------- fused prep (one launch):
// [0,512): init_out (b2 part + bias)   [512,1536): MLP -> H
// [1536,1664): dtT direct from d1,d2   [1664,2944): d1 -> d1T transpose
// [2944,2960): d2 -> d2T               [2960,4112): W2 -> Bp permute
__global__ __launch_bounds__(256)
void k_prep(const float* __restrict__ wgt, const float* __restrict__ W0,
            const float* __restrict__ b0, const float* __restrict__ W1,
            const float* __restrict__ b1, const float* __restrict__ W2,
            const float* __restrict__ b2, const float* __restrict__ bias,
            const float* __restrict__ d1, const float* __restrict__ d2,
            float* __restrict__ H, unsigned short* __restrict__ Bp,
            float* __restrict__ d1T, float* __restrict__ d2T,
            float* __restrict__ dtT, float* __restrict__ out) {
  __shared__ __align__(16) float shm[6400];
  const int bid = blockIdx.x;
  const int tid = threadIdx.x;

  if (bid < 512) {
    // ---- init_out
    float* s1s = shm;            // [8][128]
    float* v1s = shm + 1024;     // [8][64][3]
    float* dts = shm + 2560;     // [8][64]
    float* s2s = shm + 3072;     // [8]
    float* v2s = shm + 3080;     // [8][3]
    const int e0 = bid * 8;
    for (int x = tid; x < 8 * 320; x += 256) {
      int e = x / 320, c = x % 320;
      float v = d1[(size_t)(e0 + e) * 320 + c];
      if (c < 128) s1s[e * 128 + c] = v;
      else { int q = c - 128; v1s[(e * 64 + q / 3) * 3 + q % 3] = v; }
    }
    if (tid < 32) {
      int e = tid >> 2, c = tid & 3;
      float v = d2[(size_t)(e0 + e) * 4 + c];
      if (c == 0) s2s[e] = v; else v2s[e * 3 + c - 1] = v;
    }
    __syncthreads();
    for (int x = tid; x < 8 * 64; x += 256) {
      int e = x >> 6, u = x & 63;
      dts[e * 64 + u] = v1s[(e * 64 + u) * 3] * v2s[e * 3] +
                        v1s[(e * 64 + u) * 3 + 1] * v2s[e * 3 + 1] +
                        v1s[(e * 64 + u) * 3 + 2] * v2s[e * 3 + 2];
    }
    __syncthreads();
    for (int c = tid; c < 320; c += 256) {
      if (c < 128) {
        const int w = c;
        float ta[8] = {0,0,0,0,0,0,0,0}, td[8] = {0,0,0,0,0,0,0,0};
        for (int u = 0; u < 128; ++u) {
          float bv = b2[u * 128 + w];
#pragma unroll
          for (int e = 0; e < 8; ++e) ta[e] = fmaf(s1s[e * 128 + u], bv, ta[e]);
        }
        for (int u = 0; u < 64; ++u) {
          float bv = b2[N1 + N2 + N3 + u * 128 + w];
#pragma unroll
          for (int e = 0; e < 8; ++e) td[e] = fmaf(dts[e * 64 + u], bv, td[e]);
        }
        const float bw = bias[w];
#pragma unroll
        for (int e = 0; e < 8; ++e)
          out[(size_t)(e0 + e) * 320 + c] = fmaf(s2s[e], ta[e], ISQ3 * td[e]) + bw;
      } else {
        const int q = c - 128, w = q / 3, i = q % 3;
        float tb[8] = {0,0,0,0,0,0,0,0}, tc[8] = {0,0,0,0,0,0,0,0};
        for (int u = 0; u < 128; ++u) {
          float bv = b2[N1 + u * 64 + w];
#pragma unroll
          for (int e = 0; e < 8; ++e) tb[e] = fmaf(s1s[e * 128 + u], bv, tb[e]);
        }
        for (int u = 0; u < 64; ++u) {
          float bv = b2[N1 + N2 + u * 64 + w];
#pragma unroll
          for (int e = 0; e < 8; ++e) tc[e] = fmaf(v1s[(e * 64 + u) * 3 + i], bv, tc[e]);
        }
#pragma unroll
        for (int e = 0; e < 8; ++e)
          out[(size_t)(e0 + e) * 320 + c] = tb[e] * v2s[e * 3 + i] + tc[e] * s2s[e];
      }
    }
  } else if (bid < 1536) {
    // ---- MLP
    float* h0s = shm;   // [4][64]
    const int r = tid >> 6, j = tid & 63;
    const int e = (bid - 512) * 4 + r;
    float a = b0[j];
#pragma unroll
    for (int i = 0; i < 16; ++i) a = fmaf(wgt[e * 16 + i], W0[i * 64 + j], a);
    h0s[r * 64 + j] = fmaxf(a, 0.f);
    __syncthreads();
    float a1 = b1[j];
#pragma unroll
    for (int i = 0; i < 64; ++i) a1 = fmaf(h0s[r * 64 + i], W1[i * 64 + j], a1);
    H[e * 64 + j] = fmaxf(a1, 0.f);
  } else if (bid < 1664) {
    // ---- dtT[u][e] = sum_i v1[e][u][i]*v2[e][i], direct from d1/d2
    float* ld = shm;            // [32][196] (padded)
    float* sv2 = shm + 6272;    // [32][4]
    const int e0 = (bid - 1536) * 32;
    for (int x = tid; x < 1536; x += 256) {
      int e = x / 48, c4 = x % 48;
      *(f32x4*)(ld + e * 196 + c4 * 4) =
          *(const f32x4*)(d1 + (size_t)(e0 + e) * 320 + 128 + c4 * 4);
    }
    if (tid < 128) sv2[tid] = d2[(size_t)e0 * 4 + tid];
    __syncthreads();
    for (int x = tid; x < 2048; x += 256) {
      int u = x >> 5, e = x & 31;
      float acc = ld[e * 196 + 3 * u] * sv2[e * 4 + 1] +
                  ld[e * 196 + 3 * u + 1] * sv2[e * 4 + 2] +
                  ld[e * 196 + 3 * u + 2] * sv2[e * 4 + 3];
      dtT[(size_t)u * 4096 + e0 + e] = acc;
    }
  } else if (bid < 2944) {
    // ---- d1 -> d1T
    float* tile = shm;   // [32][33]
    const int tb = bid - 1664;
    const int er = tb / 10, cr = tb % 10;
    const int tr = tid >> 5, tc = tid & 31;
#pragma unroll
    for (int k = 0; k < 4; ++k) {
      int row = tr + k * 8;
      tile[row * 33 + tc] = d1[(size_t)(er * 32 + row) * 320 + cr * 32 + tc];
    }
    __syncthreads();
#pragma unroll
    for (int k = 0; k < 4; ++k) {
      int row = tr + k * 8;
      d1T[(size_t)(cr * 32 + row) * 4096 + er * 32 + tc] = tile[tc * 33 + row];
    }
  } else if (bid < 2960) {
    // ---- d2 -> d2T
    const int e = (bid - 2944) * 256 + tid;
#pragma unroll
    for (int c = 0; c < 4; ++c) d2T[c * 4096 + e] = d2[(size_t)e * 4 + c];
  } else {
    // ---- W2 -> Bp permute
    const int g = (bid - 2960) * 256 + tid;
    const int lane = g & 63;
    const int nth = g >> 6;
    const int kh = nth & 1, nt = nth >> 1;
    const int n = nt * 16 + (lane & 15);
    const int k0 = kh * 32 + (lane >> 4) * 8;
    short8 v;
#pragma unroll
    for (int j = 0; j < 8; ++j) v[j] = (short)f2bf(W2[(size_t)(k0 + j) * WN + n]);
    *(short8*)(Bp + (size_t)g * 8) = v;
  }
}

// ---------------- main: column-group decomposition, LDS scales, 2-body prefetch ring ----------------
// 1536 blocks = 128 e-tiles x 12 col-groups (8 AD + 4 BC); 4 waves split u; LDS reduce; out +=

#define AD_BODY(T, A0, A1, A2, A3, D0, D1) do {                                   \
    const int ua_ = uA0 + 2 * (T); const int ud_ = uD0 + (T);                     \
    f32x4 t0 = {0.f,0.f,0.f,0.f}, t1 = {0.f,0.f,0.f,0.f};                         \
    t0 = MFMA(hA00, A0, t0); t0 = MFMA(hA01, A1, t0);                             \
    t1 = MFMA(hA10, A0, t1); t1 = MFMA(hA11, A1, t1);                             \
    accA0 += sA4[ua_ * 8 + grp] * t0;  accA1 += sA4[ua_ * 8 + 4 + grp] * t1;      \
    f32x4 t2 = {0.f,0.f,0.f,0.f}, t3 = {0.f,0.f,0.f,0.f};                         \
    t2 = MFMA(hA00, A2, t2); t2 = MFMA(hA01, A3, t2);                             \
    t3 = MFMA(hA10, A2, t3); t3 = MFMA(hA11, A3, t3);                             \
    accA0 += sA4[(ua_ + 1) * 8 + grp] * t2; accA1 += sA4[(ua_ + 1) * 8 + 4 + grp] * t3; \
    f32x4 t4 = {0.f,0.f,0.f,0.f}, t5 = {0.f,0.f,0.f,0.f};                         \
    t4 = MFMA(hA00, D0, t4); t4 = MFMA(hA01, D1, t4);                             \
    t5 = MFMA(hA10, D0, t5); t5 = MFMA(hA11, D1, t5);                             \
    accD0 += sX4[ud_ * 8 + grp] * t4; accD1 += sX4[ud_ * 8 + 4 + grp] * t5;       \
  } while (0)

#define BC_BODY(T, B0, B1, B2, B3, C0, C1) do {                                   \
    const int ub_ = uA0 + 2 * (T); const int uc_ = uD0 + (T);                     \
    f32x4 t0 = {0.f,0.f,0.f,0.f}, t1 = {0.f,0.f,0.f,0.f};                         \
    t0 = MFMA(hA00, B0, t0); t0 = MFMA(hA01, B1, t0);                             \
    t1 = MFMA(hA10, B0, t1); t1 = MFMA(hA11, B1, t1);                             \
    accB0 += sA4[ub_ * 8 + grp] * t0;  accB1 += sA4[ub_ * 8 + 4 + grp] * t1;      \
    f32x4 t2 = {0.f,0.f,0.f,0.f}, t3 = {0.f,0.f,0.f,0.f};                         \
    t2 = MFMA(hA00, B2, t2); t2 = MFMA(hA01, B3, t2);                             \
    t3 = MFMA(hA10, B2, t3); t3 = MFMA(hA11, B3, t3);                             \
    accB0 += sA4[(ub_ + 1) * 8 + grp] * t2; accB1 += sA4[(ub_ + 1) * 8 + 4 + grp] * t3; \
    f32x4 t4 = {0.f,0.f,0.f,0.f}, t5 = {0.f,0.f,0.f,0.f};                         \
    t4 = MFMA(hA00, C0, t4); t4 = MFMA(hA01, C1, t4);                             \
    t5 = MFMA(hA10, C0, t5); t5 = MFMA(hA11, C1, t5);                             \
    c00 += sX4[(3 * uc_) * 8 + grp] * t4;                                         \
    c01 += sX4[(3 * uc_ + 1) * 8 + grp] * t4;                                     \
    c02 += sX4[(3 * uc_ + 2) * 8 + grp] * t4;                                     \
    c10 += sX4[(3 * uc_) * 8 + 4 + grp] * t5;                                     \
    c11 += sX4[(3 * uc_ + 1) * 8 + 4 + grp] * t5;                                 \
    c12 += sX4[(3 * uc_ + 2) * 8 + 4 + grp] * t5;                                 \
  } while (0)

__global__ __launch_bounds__(256, 4)
void k_main(const float* __restrict__ d1T, const float* __restrict__ d2T,
            const float* __restrict__ dtT, const float* __restrict__ H,
            const unsigned short* __restrict__ Bp, float* __restrict__ out) {
  const int i = blockIdx.x;
  const int g8 = i & 7;
  const int jj = i >> 3;
  int g, et;
  if (jj < 128) { g = g8; et = jj; }
  else { g = 8 + (g8 & 3); et = ((jj - 128) << 1) + (g8 >> 2); }
  const int e0 = et * 32;
  const int tid = threadIdx.x;
  const int wid = tid >> 6, lane = tid & 63;
  const int nl = lane & 15, grp = lane >> 4;

  __shared__ __align__(16) float lds[10240];        // 40960 B: sA[1024 f32x4] + sX[1536 f32x4]
  f32x4* sA4 = (f32x4*)lds;                         // [128][8]  (s1 scales)
  f32x4* sX4 = (f32x4*)(lds + 4096);                // AD: dt [64][8]; BC: v1 [192][8]
  float* redp = lds;                                // alias (post-barrier reduction)

  // stage scales (coalesced)
  {
    const f32x4* src = (const f32x4*)(d1T + e0);
    for (int x = tid; x < 1024; x += 256) sA4[x] = src[(size_t)(x >> 3) * 1024 + (x & 7)];
    if (g < 8) {
      const f32x4* s2 = (const f32x4*)(dtT + e0);
      for (int x = tid; x < 512; x += 256) sX4[x] = s2[(size_t)(x >> 3) * 1024 + (x & 7)];
    } else {
      const f32x4* s2 = (const f32x4*)(d1T + (size_t)128 * 4096 + e0);
      for (int x = tid; x < 1536; x += 256) sX4[x] = s2[(size_t)(x >> 3) * 1024 + (x & 7)];
    }
  }

  // A-frags from H (register-resident)
  short8 hA00, hA01, hA10, hA11;
  {
    const float* hp0 = H + (size_t)(e0 + nl) * 64 + grp * 8;
    const float* hp1 = H + (size_t)(e0 + 16 + nl) * 64 + grp * 8;
    short8 v;
#pragma unroll
    for (int j = 0; j < 8; ++j) v[j] = (short)f2bf(hp0[j]);      hA00 = v;
#pragma unroll
    for (int j = 0; j < 8; ++j) v[j] = (short)f2bf(hp0[32 + j]); hA01 = v;
#pragma unroll
    for (int j = 0; j < 8; ++j) v[j] = (short)f2bf(hp1[j]);      hA10 = v;
#pragma unroll
    for (int j = 0; j < 8; ++j) v[j] = (short)f2bf(hp1[32 + j]); hA11 = v;
  }

  const short8* Bp8 = (const short8*)Bp;
  const int uA0 = wid * 32;   // A/B u-range per wave
  const int uD0 = wid * 16;   // D/C u-range per wave

  if (g < 8) {
    const int j = g;
    const short8* pA = Bp8 + (size_t)(uA0 * 8 + j) * 128 + lane;
    const short8* pD = Bp8 + (size_t)(1792 + uD0 * 8 + j) * 128 + lane;
    // preload bodies 0,1
    short8 ra0 = pA[0],    ra1 = pA[64],   ra2 = pA[1024], ra3 = pA[1088];
    short8 rb0 = pA[2048], rb1 = pA[2112], rb2 = pA[3072], rb3 = pA[3136];
    short8 rd0 = pD[0],    rd1 = pD[64];
    short8 re0 = pD[1024], re1 = pD[1088];
    pA += 4096; pD += 2048;

    __syncthreads();

    f32x4 accA0 = {}, accA1 = {}, accD0 = {}, accD1 = {};
#pragma unroll
    for (int t = 0; t < 16; t += 2) {
      AD_BODY(t, ra0, ra1, ra2, ra3, rd0, rd1);
      if (t < 14) {
        ra0 = pA[0]; ra1 = pA[64]; ra2 = pA[1024]; ra3 = pA[1088]; pA += 2048;
        rd0 = pD[0]; rd1 = pD[64]; pD += 1024;
      }
      AD_BODY(t + 1, rb0, rb1, rb2, rb3, re0, re1);
      if (t < 13) {
        rb0 = pA[0]; rb1 = pA[64]; rb2 = pA[1024]; rb3 = pA[1088]; pA += 2048;
        re0 = pD[0]; re1 = pD[64]; pD += 1024;
      }
    }

    __syncthreads();   // lds reused as red
#pragma unroll
    for (int r = 0; r < 4; ++r) {
      float* rp = redp + ((size_t)wid * 64 + lane) * 33;
      rp[r] = accA0[r]; rp[4 + r] = accA1[r]; rp[8 + r] = accD0[r]; rp[12 + r] = accD1[r];
    }
    __syncthreads();
    for (int oidx = tid; oidx < 512; oidx += 256) {
      const int e = oidx >> 4, w = oidx & 15;
      const int m = e >> 4, gr = (e >> 2) & 3, r = e & 3;
      const int ln = gr * 16 + w;
      float ta = 0.f, td = 0.f;
#pragma unroll
      for (int t = 0; t < 4; ++t) {
        const float* rp = redp + ((size_t)t * 64 + ln) * 33;
        ta += rp[m * 4 + r]; td += rp[8 + m * 4 + r];
      }
      const float s2 = d2T[e0 + e];
      out[(size_t)(e0 + e) * 320 + j * 16 + w] += s2 * ta + ISQ3 * td;
    }
  } else {
    const int j = g - 8;
    const short8* pB = Bp8 + (size_t)(1024 + uA0 * 4 + j) * 128 + lane;
    const short8* pC = Bp8 + (size_t)(1536 + uD0 * 4 + j) * 128 + lane;
    short8 ra0 = pB[0],    ra1 = pB[64],   ra2 = pB[512],  ra3 = pB[576];
    short8 rb0 = pB[1024], rb1 = pB[1088], rb2 = pB[1536], rb3 = pB[1600];
    short8 rc0 = pC[0],    rc1 = pC[64];
    short8 rd0 = pC[512],  rd1 = pC[576];
    pB += 2048; pC += 1024;

    __syncthreads();

    f32x4 accB0 = {}, accB1 = {};
    f32x4 c00 = {}, c01 = {}, c02 = {}, c10 = {}, c11 = {}, c12 = {};
#pragma unroll
    for (int t = 0; t < 16; t += 2) {
      BC_BODY(t, ra0, ra1, ra2, ra3, rc0, rc1);
      if (t < 14) {
        ra0 = pB[0]; ra1 = pB[64]; ra2 = pB[512]; ra3 = pB[576]; pB += 1024;
        rc0 = pC[0]; rc1 = pC[64]; pC += 512;
      }
      BC_BODY(t + 1, rb0, rb1, rb2, rb3, rd0, rd1);
      if (t < 13) {
        rb0 = pB[0]; rb1 = pB[64]; rb2 = pB[512]; rb3 = pB[576]; pB += 1024;
        rd0 = pC[0]; rd1 = pC[64]; pC += 512;
      }
    }

    __syncthreads();   // lds reused as red
#pragma unroll
    for (int r = 0; r < 4; ++r) {
      float* rp = redp + ((size_t)wid * 64 + lane) * 33;
      rp[r] = accB0[r];      rp[4 + r] = accB1[r];
      rp[8 + r] = c00[r];    rp[12 + r] = c01[r];  rp[16 + r] = c02[r];
      rp[20 + r] = c10[r];   rp[24 + r] = c11[r];  rp[28 + r] = c12[r];
    }
    __syncthreads();
    for (int oidx = tid; oidx < 1536; oidx += 256) {
      const int e = oidx / 48, rem = oidx % 48;
      const int w = rem / 3, ii = rem % 3;
      const int m = e >> 4, gr = (e >> 2) & 3, r = e & 3;
      const int ln = gr * 16 + w;
      float tb = 0.f, tc = 0.f;
#pragma unroll
      for (int t = 0; t < 4; ++t) {
        const float* rp = redp + ((size_t)t * 64 + ln) * 33;
        tb += rp[m * 4 + r];
        tc += rp[8 + (m * 3 + ii) * 4 + r];
      }
      const float s2 = d2T[e0 + e];
      const float v2 = d2T[(1 + ii) * 4096 + e0 + e];
      out[(size_t)(e0 + e) * 320 + 128 + j * 48 + 3 * w + ii] += tb * v2 + tc * s2;
    }
  }
}

extern "C" void kernel_launch(void* const* d_in, const int* in_sizes, int n_in,
                              void* d_out, int out_size, void* d_ws, size_t ws_size,
                              hipStream_t stream) {
  const float* d1   = (const float*)d_in[0];
  const float* d2   = (const float*)d_in[1];
  const float* wgt  = (const float*)d_in[2];
  const float* W0   = (const float*)d_in[3];
  const float* b0   = (const float*)d_in[4];
  const float* W1   = (const float*)d_in[5];
  const float* b1   = (const float*)d_in[6];
  const float* W2   = (const float*)d_in[7];
  const float* b2   = (const float*)d_in[8];
  const float* bias = (const float*)d_in[9];
  float* out = (float*)d_out;

  char* ws = (char*)d_ws;
  float* H           = (float*)(ws);                        // 1 MiB
  unsigned short* Bp = (unsigned short*)(ws + (1u << 20));  // 4.72 MB
  float* d1T         = (float*)(ws + (8u << 20));           // 5.24 MB
  float* dtT         = (float*)(ws + (16u << 20));          // 1 MB
  float* d2T         = (float*)(ws + (20u << 20));          // 64 KB

  k_prep<<<4112, 256, 0, stream>>>(wgt, W0, b0, W1, b1, W2, b2, bias, d1, d2,
                                   H, Bp, d1T, d2T, dtT, out);
  k_main<<<1536, 256, 0, stream>>>(d1T, d2T, dtT, H, Bp, out);
}

// Round 6
// 73.862 us; speedup vs baseline: 4.1701x; 1.1121x over previous
//
#include <hip/hip_runtime.h>
#include <hip/hip_bf16.h>

typedef __attribute__((ext_vector_type(8))) short short8;   // bf16x8 MFMA frag
typedef __attribute__((ext_vector_type(4))) float f32x4;

constexpr int N1 = 16384, N2 = 8192, N3 = 4096;
constexpr int WN = 36864;
constexpr float ISQ3 = 0.57735026918962576451f;

__device__ __forceinline__ unsigned short f2bf(float f) {
  unsigned u = __builtin_bit_cast(unsigned, f);
  u += 0x7fffu + ((u >> 16) & 1u);   // RNE
  return (unsigned short)(u >> 16);
}

#define MFMA(a, b, c) __builtin_amdgcn_mfma_f32_16x16x32_bf16((a), (b), (c), 0, 0, 0)

// ---------------- fused prep (one launch):
// [0,512): init_out (b2 part + bias)    [512,1664): W2 -> Bp permute
// [1664,2688): MLP -> H                 [2688,2816): scale buffers
__global__ __launch_bounds__(256)
void k_prep(const float* __restrict__ wgt, const float* __restrict__ W0,
            const float* __restrict__ b0, const float* __restrict__ W1,
            const float* __restrict__ b1, const float* __restrict__ W2,
            const float* __restrict__ b2, const float* __restrict__ bias,
            const float* __restrict__ d1, const float* __restrict__ d2,
            float* __restrict__ H, unsigned short* __restrict__ Bp,
            float* __restrict__ sAg, float* __restrict__ sBg,
            float* __restrict__ sDg, float* __restrict__ sCg,
            float* __restrict__ d2T, float* __restrict__ out) {
  __shared__ __align__(16) float shm[10400];
  const int bid = blockIdx.x;
  const int tid = threadIdx.x;

  if (bid < 512) {
    // ---- init_out: b2-contraction + bias (fully overwrites d_out)
    float* s1s = shm;            // [8][128]
    float* v1s = shm + 1024;     // [8][64][3]
    float* dts = shm + 2560;     // [8][64]
    float* s2s = shm + 3072;     // [8]
    float* v2s = shm + 3080;     // [8][3]
    const int e0 = bid * 8;
    for (int x = tid; x < 8 * 320; x += 256) {
      int e = x / 320, c = x % 320;
      float v = d1[(size_t)(e0 + e) * 320 + c];
      if (c < 128) s1s[e * 128 + c] = v;
      else { int q = c - 128; v1s[(e * 64 + q / 3) * 3 + q % 3] = v; }
    }
    if (tid < 32) {
      int e = tid >> 2, c = tid & 3;
      float v = d2[(size_t)(e0 + e) * 4 + c];
      if (c == 0) s2s[e] = v; else v2s[e * 3 + c - 1] = v;
    }
    __syncthreads();
    for (int x = tid; x < 8 * 64; x += 256) {
      int e = x >> 6, u = x & 63;
      dts[e * 64 + u] = v1s[(e * 64 + u) * 3] * v2s[e * 3] +
                        v1s[(e * 64 + u) * 3 + 1] * v2s[e * 3 + 1] +
                        v1s[(e * 64 + u) * 3 + 2] * v2s[e * 3 + 2];
    }
    __syncthreads();
    for (int c = tid; c < 320; c += 256) {
      if (c < 128) {
        const int w = c;
        float ta[8] = {0,0,0,0,0,0,0,0}, td[8] = {0,0,0,0,0,0,0,0};
        for (int u = 0; u < 128; ++u) {
          float bv = b2[u * 128 + w];
#pragma unroll
          for (int e = 0; e < 8; ++e) ta[e] = fmaf(s1s[e * 128 + u], bv, ta[e]);
        }
        for (int u = 0; u < 64; ++u) {
          float bv = b2[N1 + N2 + N3 + u * 128 + w];
#pragma unroll
          for (int e = 0; e < 8; ++e) td[e] = fmaf(dts[e * 64 + u], bv, td[e]);
        }
        const float bw = bias[w];
#pragma unroll
        for (int e = 0; e < 8; ++e)
          out[(size_t)(e0 + e) * 320 + c] = fmaf(s2s[e], ta[e], ISQ3 * td[e]) + bw;
      } else {
        const int q = c - 128, w = q / 3, i = q % 3;
        float tb[8] = {0,0,0,0,0,0,0,0}, tc[8] = {0,0,0,0,0,0,0,0};
        for (int u = 0; u < 128; ++u) {
          float bv = b2[N1 + u * 64 + w];
#pragma unroll
          for (int e = 0; e < 8; ++e) tb[e] = fmaf(s1s[e * 128 + u], bv, tb[e]);
        }
        for (int u = 0; u < 64; ++u) {
          float bv = b2[N1 + N2 + u * 64 + w];
#pragma unroll
          for (int e = 0; e < 8; ++e) tc[e] = fmaf(v1s[(e * 64 + u) * 3 + i], bv, tc[e]);
        }
#pragma unroll
        for (int e = 0; e < 8; ++e)
          out[(size_t)(e0 + e) * 320 + c] = tb[e] * v2s[e * 3 + i] + tc[e] * s2s[e];
      }
    }
  } else if (bid < 1664) {
    // ---- W2 -> Bp permute: Bp[((nt*2+kh)*64+lane)*8+q] = bf16(W2[kh*32+(lane>>4)*8+q][nt*16+(lane&15)])
    const int g = (bid - 512) * 256 + tid;
    const int lane = g & 63;
    const int nth = g >> 6;
    const int kh = nth & 1, nt = nth >> 1;
    const int n = nt * 16 + (lane & 15);
    const int k0 = kh * 32 + (lane >> 4) * 8;
    short8 v;
#pragma unroll
    for (int q = 0; q < 8; ++q) v[q] = (short)f2bf(W2[(size_t)(k0 + q) * WN + n]);
    *(short8*)(Bp + (size_t)g * 8) = v;
  } else if (bid < 2688) {
    // ---- MLP: H = relu(relu(weight@W0+b0)@W1+b1)
    float* h0s = shm;
    const int r = tid >> 6, jj = tid & 63;
    const int e = (bid - 1664) * 4 + r;
    float a = b0[jj];
#pragma unroll
    for (int i = 0; i < 16; ++i) a = fmaf(wgt[e * 16 + i], W0[i * 64 + jj], a);
    h0s[r * 64 + jj] = fmaxf(a, 0.f);
    __syncthreads();
    float a1 = b1[jj];
#pragma unroll
    for (int i = 0; i < 64; ++i) a1 = fmaf(h0s[r * 64 + i], W1[i * 64 + jj], a1);
    H[e * 64 + jj] = fmaxf(a1, 0.f);
  } else {
    // ---- scale buffers: sAg[u][e]=s1*s2, sBg=s1, sDg=ISQ3*dot12, sCg[3u+i][e]=v1_i*s2, d2T
    float* d1s = shm;            // [32][321]
    float* d2s = shm + 10272;    // [32][4]
    const int e0 = (bid - 2688) * 32;
    for (int x = tid; x < 32 * 320; x += 256) {
      int e = x / 320, c = x % 320;
      d1s[e * 321 + c] = d1[(size_t)(e0 + e) * 320 + c];
    }
    if (tid < 128) d2s[tid] = d2[(size_t)e0 * 4 + tid];
    __syncthreads();
    const int e = tid & 31;
    const float s2 = d2s[e * 4 + 0];
    const float w1 = d2s[e * 4 + 1], w2 = d2s[e * 4 + 2], w3 = d2s[e * 4 + 3];
    for (int row = (tid >> 5); row < 516; row += 8) {
      float v; float* dst;
      if (row < 128)      { v = d1s[e * 321 + row] * s2;            dst = sAg + (size_t)row * 4096; }
      else if (row < 256) { v = d1s[e * 321 + (row - 128)];         dst = sBg + (size_t)(row - 128) * 4096; }
      else if (row < 320) { int u = row - 256;
        v = ISQ3 * (d1s[e * 321 + 128 + 3 * u] * w1 + d1s[e * 321 + 129 + 3 * u] * w2 +
                    d1s[e * 321 + 130 + 3 * u] * w3);               dst = sDg + (size_t)u * 4096; }
      else if (row < 512) { v = d1s[e * 321 + 128 + (row - 320)] * s2; dst = sCg + (size_t)(row - 320) * 4096; }
      else                { v = d2s[e * 4 + (row - 512)];           dst = d2T + (size_t)(row - 512) * 4096; }
      dst[e0 + e] = v;
    }
  }
}

// ---------------- main: transposed MFMA (C[w,e]), per-lane scalar scales, no atomics ----------------
// bid [0,512): AD, e-tile 64, j = bid&7 (XCD-pinned), tile = bid>>3
// bid [512,1024): BC, e-tile 32, j = idx&3, tile = (idx>>3)*2 + ((idx>>2)&1)
__global__ __launch_bounds__(256, 3)
void k_main(const float* __restrict__ sAg, const float* __restrict__ sBg,
            const float* __restrict__ sDg, const float* __restrict__ sCg,
            const float* __restrict__ d2T, const float* __restrict__ H,
            const unsigned short* __restrict__ Bp, float* __restrict__ out) {
  __shared__ __align__(16) float lds[8704];
  const int bid = blockIdx.x, tid = threadIdx.x;
  const int wid = tid >> 6, lane = tid & 63;
  const int nl = lane & 15, grp = lane >> 4;
  const short8* Bp8 = (const short8*)Bp;
  const f32x4 Z = {0.f, 0.f, 0.f, 0.f};

  if (bid < 512) {
    // ================= AD path =================
    const int j = bid & 7, tile = bid >> 3, e0 = tile * 64;
    short8 h00, h01, h10, h11, h20, h21, h30, h31;
    {
      const float* hp; short8 v0, v1;
#define LOADH(EF, N0, N1_)                                                     \
      hp = H + (size_t)(e0 + 16 * EF + nl) * 64 + grp * 8;                     \
      _Pragma("unroll") for (int q = 0; q < 8; ++q) {                          \
        v0[q] = (short)f2bf(hp[q]); v1[q] = (short)f2bf(hp[32 + q]); }         \
      N0 = v0; N1_ = v1;
      LOADH(0, h00, h01) LOADH(1, h10, h11) LOADH(2, h20, h21) LOADH(3, h30, h31)
#undef LOADH
    }
    const int uA0 = wid * 32, uD0 = wid * 16;
    const short8* pA = Bp8 + (size_t)(uA0 * 8 + j) * 128 + lane;
    const short8* pD = Bp8 + (size_t)(1792 + uD0 * 8 + j) * 128 + lane;
    const float* qA0 = sAg + (size_t)uA0 * 4096 + e0 + nl;
    const float* qA1 = qA0 + 4096;
    const float* qD  = sDg + (size_t)uD0 * 4096 + e0 + nl;

    // ring set 0 (body t) and set 1 (body t+1)
    short8 A00 = pA[0], A01 = pA[64], A10 = pA[1024], A11 = pA[1088]; pA += 2048;
    short8 D00 = pD[0], D01 = pD[64]; pD += 1024;
    float sa0 = qA0[0], sa1 = qA0[16], sa2 = qA0[32], sa3 = qA0[48];
    float sa4 = qA1[0], sa5 = qA1[16], sa6 = qA1[32], sa7 = qA1[48]; qA0 += 8192; qA1 += 8192;
    float sd0 = qD[0], sd1 = qD[16], sd2 = qD[32], sd3 = qD[48]; qD += 4096;
    short8 B00 = pA[0], B01 = pA[64], B10 = pA[1024], B11 = pA[1088]; pA += 2048;
    short8 E00 = pD[0], E01 = pD[64]; pD += 1024;
    float ta0 = qA0[0], ta1 = qA0[16], ta2 = qA0[32], ta3 = qA0[48];
    float ta4 = qA1[0], ta5 = qA1[16], ta6 = qA1[32], ta7 = qA1[48]; qA0 += 8192; qA1 += 8192;
    float td0 = qD[0], td1 = qD[16], td2 = qD[32], td3 = qD[48]; qD += 4096;

    f32x4 accA[4] = {Z, Z, Z, Z};
    f32x4 accD[4] = {Z, Z, Z, Z};

#define QUAD(P0, P1, S0, S1, S2, S3, AC) do { f32x4 t_;                        \
    t_ = Z; t_ = MFMA(P0, h00, t_); t_ = MFMA(P1, h01, t_); AC[0] += (S0) * t_; \
    t_ = Z; t_ = MFMA(P0, h10, t_); t_ = MFMA(P1, h11, t_); AC[1] += (S1) * t_; \
    t_ = Z; t_ = MFMA(P0, h20, t_); t_ = MFMA(P1, h21, t_); AC[2] += (S2) * t_; \
    t_ = Z; t_ = MFMA(P0, h30, t_); t_ = MFMA(P1, h31, t_); AC[3] += (S3) * t_; } while (0)

#pragma unroll
    for (int t = 0; t < 16; t += 2) {
      QUAD(A00, A01, sa0, sa1, sa2, sa3, accA);
      QUAD(A10, A11, sa4, sa5, sa6, sa7, accA);
      QUAD(D00, D01, sd0, sd1, sd2, sd3, accD);
      if (t < 14) {
        A00 = pA[0]; A01 = pA[64]; A10 = pA[1024]; A11 = pA[1088]; pA += 2048;
        D00 = pD[0]; D01 = pD[64]; pD += 1024;
        sa0 = qA0[0]; sa1 = qA0[16]; sa2 = qA0[32]; sa3 = qA0[48];
        sa4 = qA1[0]; sa5 = qA1[16]; sa6 = qA1[32]; sa7 = qA1[48]; qA0 += 8192; qA1 += 8192;
        sd0 = qD[0]; sd1 = qD[16]; sd2 = qD[32]; sd3 = qD[48]; qD += 4096;
      }
      QUAD(B00, B01, ta0, ta1, ta2, ta3, accA);
      QUAD(B10, B11, ta4, ta5, ta6, ta7, accA);
      QUAD(E00, E01, td0, td1, td2, td3, accD);
      if (t < 13) {
        B00 = pA[0]; B01 = pA[64]; B10 = pA[1024]; B11 = pA[1088]; pA += 2048;
        E00 = pD[0]; E01 = pD[64]; pD += 1024;
        ta0 = qA0[0]; ta1 = qA0[16]; ta2 = qA0[32]; ta3 = qA0[48];
        ta4 = qA1[0]; ta5 = qA1[16]; ta6 = qA1[32]; ta7 = qA1[48]; qA0 += 8192; qA1 += 8192;
        td0 = qD[0]; td1 = qD[16]; td2 = qD[32]; td3 = qD[48]; qD += 4096;
      }
    }
#undef QUAD

    // reduce 4 waves + coalesced += : lds [4][64][20]
#pragma unroll
    for (int eF = 0; eF < 4; ++eF) {
      f32x4 fin = accA[eF] + accD[eF];
      *(f32x4*)&lds[wid * 1280 + (16 * eF + nl) * 20 + grp * 4] = fin;
    }
    __syncthreads();
    {
      const int e = tid >> 2, w4 = (tid & 3) * 4;
      f32x4 s = Z;
#pragma unroll
      for (int wv = 0; wv < 4; ++wv) s += *(const f32x4*)&lds[wv * 1280 + e * 20 + w4];
      f32x4* op = (f32x4*)(out + (size_t)(e0 + e) * 320 + j * 16 + w4);
      *op = *op + s;
    }
  } else {
    // ================= BC path =================
    const int idx = bid - 512;
    const int j = idx & 3;
    const int tile = ((idx >> 3) << 1) + ((idx >> 2) & 1);
    const int e0 = tile * 32;
    short8 h00, h01, h10, h11;
    {
      const float* hp; short8 v0, v1;
#define LOADH(EF, N0, N1_)                                                     \
      hp = H + (size_t)(e0 + 16 * EF + nl) * 64 + grp * 8;                     \
      _Pragma("unroll") for (int q = 0; q < 8; ++q) {                          \
        v0[q] = (short)f2bf(hp[q]); v1[q] = (short)f2bf(hp[32 + q]); }         \
      N0 = v0; N1_ = v1;
      LOADH(0, h00, h01) LOADH(1, h10, h11)
#undef LOADH
    }
    const int uB0 = wid * 32, uC0 = wid * 16;
    const short8* pB = Bp8 + (size_t)(1024 + uB0 * 4 + j) * 128 + lane;
    const short8* pC = Bp8 + (size_t)(1536 + uC0 * 4 + j) * 128 + lane;
    const float* qB0 = sBg + (size_t)uB0 * 4096 + e0 + nl;
    const float* qB1 = qB0 + 4096;
    const float* qC0 = sCg + (size_t)(uC0 * 3) * 4096 + e0 + nl;
    const float* qC1 = qC0 + 4096;
    const float* qC2 = qC0 + 8192;

    short8 A00 = pB[0], A01 = pB[64], A10 = pB[512], A11 = pB[576]; pB += 1024;
    short8 C00 = pC[0], C01 = pC[64]; pC += 512;
    float sb0 = qB0[0], sb1 = qB0[16], sb2 = qB1[0], sb3 = qB1[16]; qB0 += 8192; qB1 += 8192;
    float sc00 = qC0[0], sc01 = qC0[16], sc10 = qC1[0], sc11 = qC1[16],
          sc20 = qC2[0], sc21 = qC2[16]; qC0 += 12288; qC1 += 12288; qC2 += 12288;
    short8 B00 = pB[0], B01 = pB[64], B10 = pB[512], B11 = pB[576]; pB += 1024;
    short8 E00 = pC[0], E01 = pC[64]; pC += 512;
    float tb0 = qB0[0], tb1 = qB0[16], tb2 = qB1[0], tb3 = qB1[16]; qB0 += 8192; qB1 += 8192;
    float tc00 = qC0[0], tc01 = qC0[16], tc10 = qC1[0], tc11 = qC1[16],
          tc20 = qC2[0], tc21 = qC2[16]; qC0 += 12288; qC1 += 12288; qC2 += 12288;

    f32x4 accB[2] = {Z, Z};
    f32x4 accC0[2] = {Z, Z}, accC1[2] = {Z, Z}, accC2[2] = {Z, Z};

#define DUO(P0, P1, S0, S1) do { f32x4 t_;                                     \
    t_ = Z; t_ = MFMA(P0, h00, t_); t_ = MFMA(P1, h01, t_); accB[0] += (S0) * t_; \
    t_ = Z; t_ = MFMA(P0, h10, t_); t_ = MFMA(P1, h11, t_); accB[1] += (S1) * t_; } while (0)
#define CTRIO(P0, P1, X00, X01, X10, X11, X20, X21) do { f32x4 u0_, u1_;       \
    u0_ = Z; u0_ = MFMA(P0, h00, u0_); u0_ = MFMA(P1, h01, u0_);               \
    u1_ = Z; u1_ = MFMA(P0, h10, u1_); u1_ = MFMA(P1, h11, u1_);               \
    accC0[0] += (X00) * u0_; accC0[1] += (X01) * u1_;                          \
    accC1[0] += (X10) * u0_; accC1[1] += (X11) * u1_;                          \
    accC2[0] += (X20) * u0_; accC2[1] += (X21) * u1_; } while (0)

#pragma unroll
    for (int t = 0; t < 16; t += 2) {
      DUO(A00, A01, sb0, sb1);
      DUO(A10, A11, sb2, sb3);
      CTRIO(C00, C01, sc00, sc01, sc10, sc11, sc20, sc21);
      if (t < 14) {
        A00 = pB[0]; A01 = pB[64]; A10 = pB[512]; A11 = pB[576]; pB += 1024;
        C00 = pC[0]; C01 = pC[64]; pC += 512;
        sb0 = qB0[0]; sb1 = qB0[16]; sb2 = qB1[0]; sb3 = qB1[16]; qB0 += 8192; qB1 += 8192;
        sc00 = qC0[0]; sc01 = qC0[16]; sc10 = qC1[0]; sc11 = qC1[16];
        sc20 = qC2[0]; sc21 = qC2[16]; qC0 += 12288; qC1 += 12288; qC2 += 12288;
      }
      DUO(B00, B01, tb0, tb1);
      DUO(B10, B11, tb2, tb3);
      CTRIO(E00, E01, tc00, tc01, tc10, tc11, tc20, tc21);
      if (t < 13) {
        B00 = pB[0]; B01 = pB[64]; B10 = pB[512]; B11 = pB[576]; pB += 1024;
        E00 = pC[0]; E01 = pC[64]; pC += 512;
        tb0 = qB0[0]; tb1 = qB0[16]; tb2 = qB1[0]; tb3 = qB1[16]; qB0 += 8192; qB1 += 8192;
        tc00 = qC0[0]; tc01 = qC0[16]; tc10 = qC1[0]; tc11 = qC1[16];
        tc20 = qC2[0]; tc21 = qC2[16]; qC0 += 12288; qC1 += 12288; qC2 += 12288;
      }
    }
#undef DUO
#undef CTRIO

    // reduce 4 waves + epilogue: lds [4][32][68], slots {tb, tc0, tc1, tc2} per (e,w)
#pragma unroll
    for (int eF = 0; eF < 2; ++eF)
#pragma unroll
      for (int r = 0; r < 4; ++r) {
        f32x4 v = {accB[eF][r], accC0[eF][r], accC1[eF][r], accC2[eF][r]};
        *(f32x4*)&lds[wid * 2176 + (16 * eF + nl) * 68 + (grp * 4 + r) * 4] = v;
      }
    __syncthreads();
    for (int p = tid; p < 512; p += 256) {
      const int e = p >> 4, w = p & 15;
      f32x4 s = Z;
#pragma unroll
      for (int wv = 0; wv < 4; ++wv) s += *(const f32x4*)&lds[wv * 2176 + e * 68 + w * 4];
      const float v20 = d2T[4096 + e0 + e], v21 = d2T[8192 + e0 + e], v22 = d2T[12288 + e0 + e];
      float* op = out + (size_t)(e0 + e) * 320 + 128 + (size_t)(j * 16 + w) * 3;
      op[0] += s[0] * v20 + s[1];
      op[1] += s[0] * v21 + s[2];
      op[2] += s[0] * v22 + s[3];
    }
  }
}

extern "C" void kernel_launch(void* const* d_in, const int* in_sizes, int n_in,
                              void* d_out, int out_size, void* d_ws, size_t ws_size,
                              hipStream_t stream) {
  const float* d1   = (const float*)d_in[0];
  const float* d2   = (const float*)d_in[1];
  const float* wgt  = (const float*)d_in[2];
  const float* W0   = (const float*)d_in[3];
  const float* b0   = (const float*)d_in[4];
  const float* W1   = (const float*)d_in[5];
  const float* b1   = (const float*)d_in[6];
  const float* W2   = (const float*)d_in[7];
  const float* b2   = (const float*)d_in[8];
  const float* bias = (const float*)d_in[9];
  float* out = (float*)d_out;

  char* ws = (char*)d_ws;
  float* H           = (float*)(ws);                         // 1 MiB
  unsigned short* Bp = (unsigned short*)(ws + (1u << 20));   // 4.72 MB
  float* sAg         = (float*)(ws + (6u << 20));            // 2 MB  [128][4096] s1*s2
  float* sBg         = (float*)(ws + (8u << 20));            // 2 MB  [128][4096] s1
  float* sDg         = (float*)(ws + (10u << 20));           // 1 MB  [64][4096]  ISQ3*dot12
  float* sCg         = (float*)(ws + (11u << 20));           // 3 MB  [192][4096] v1_i*s2
  float* d2T         = (float*)(ws + (14u << 20));           // 64 KB [4][4096]

  k_prep<<<2816, 256, 0, stream>>>(wgt, W0, b0, W1, b1, W2, b2, bias, d1, d2,
                                   H, Bp, sAg, sBg, sDg, sCg, d2T, out);
  k_main<<<1024, 256, 0, stream>>>(sAg, sBg, sDg, sCg, d2T, H, Bp, out);
}

// Round 7
// 67.709 us; speedup vs baseline: 4.5491x; 1.0909x over previous
//
#include <hip/hip_runtime.h>
#include <hip/hip_bf16.h>

typedef __attribute__((ext_vector_type(8))) short short8;   // bf16x8 MFMA frag
typedef __attribute__((ext_vector_type(4))) float f32x4;
typedef __attribute__((ext_vector_type(4))) unsigned uint4v;

constexpr int N1 = 16384, N2 = 8192, N3 = 4096;
constexpr int WN = 36864;
constexpr float ISQ3 = 0.57735026918962576451f;

__device__ __forceinline__ unsigned short f2bf(float f) {
  unsigned u = __builtin_bit_cast(unsigned, f);
  u += 0x7fffu + ((u >> 16) & 1u);   // RNE
  return (unsigned short)(u >> 16);
}

// packed RNE f32x2 -> bf16x2 (single HW instruction)
__device__ __forceinline__ unsigned pkbf(float a, float b) {
  unsigned r;
  asm("v_cvt_pk_bf16_f32 %0, %1, %2" : "=v"(r) : "v"(a), "v"(b));
  return r;
}

#define MFMA(a, b, c) __builtin_amdgcn_mfma_f32_16x16x32_bf16((a), (b), (c), 0, 0, 0)

// scale 16 f32 h-values by S, pack to two bf16x8 frags (kh0: k0..7, kh1: k8..15)
#define SYNTH(S, HF, G0, G1) do {                                                   \
    uint4v w0_, w1_;                                                                \
    w0_[0] = pkbf((S)*HF[0],  (S)*HF[1]);   w0_[1] = pkbf((S)*HF[2],  (S)*HF[3]);   \
    w0_[2] = pkbf((S)*HF[4],  (S)*HF[5]);   w0_[3] = pkbf((S)*HF[6],  (S)*HF[7]);   \
    w1_[0] = pkbf((S)*HF[8],  (S)*HF[9]);   w1_[1] = pkbf((S)*HF[10], (S)*HF[11]);  \
    w1_[2] = pkbf((S)*HF[12], (S)*HF[13]);  w1_[3] = pkbf((S)*HF[14], (S)*HF[15]);  \
    G0 = __builtin_bit_cast(short8, w0_);   G1 = __builtin_bit_cast(short8, w1_);   \
  } while (0)

// ---------------- fused prep (one launch) — unchanged from R6 (proven) ----------------
__global__ __launch_bounds__(256)
void k_prep(const float* __restrict__ wgt, const float* __restrict__ W0,
            const float* __restrict__ b0, const float* __restrict__ W1,
            const float* __restrict__ b1, const float* __restrict__ W2,
            const float* __restrict__ b2, const float* __restrict__ bias,
            const float* __restrict__ d1, const float* __restrict__ d2,
            float* __restrict__ H, unsigned short* __restrict__ Bp,
            float* __restrict__ sAg, float* __restrict__ sBg,
            float* __restrict__ sDg, float* __restrict__ sCg,
            float* __restrict__ d2T, float* __restrict__ out) {
  __shared__ __align__(16) float shm[10400];
  const int bid = blockIdx.x;
  const int tid = threadIdx.x;

  if (bid < 512) {
    float* s1s = shm;            // [8][128]
    float* v1s = shm + 1024;     // [8][64][3]
    float* dts = shm + 2560;     // [8][64]
    float* s2s = shm + 3072;     // [8]
    float* v2s = shm + 3080;     // [8][3]
    const int e0 = bid * 8;
    for (int x = tid; x < 8 * 320; x += 256) {
      int e = x / 320, c = x % 320;
      float v = d1[(size_t)(e0 + e) * 320 + c];
      if (c < 128) s1s[e * 128 + c] = v;
      else { int q = c - 128; v1s[(e * 64 + q / 3) * 3 + q % 3] = v; }
    }
    if (tid < 32) {
      int e = tid >> 2, c = tid & 3;
      float v = d2[(size_t)(e0 + e) * 4 + c];
      if (c == 0) s2s[e] = v; else v2s[e * 3 + c - 1] = v;
    }
    __syncthreads();
    for (int x = tid; x < 8 * 64; x += 256) {
      int e = x >> 6, u = x & 63;
      dts[e * 64 + u] = v1s[(e * 64 + u) * 3] * v2s[e * 3] +
                        v1s[(e * 64 + u) * 3 + 1] * v2s[e * 3 + 1] +
                        v1s[(e * 64 + u) * 3 + 2] * v2s[e * 3 + 2];
    }
    __syncthreads();
    for (int c = tid; c < 320; c += 256) {
      if (c < 128) {
        const int w = c;
        float ta[8] = {0,0,0,0,0,0,0,0}, td[8] = {0,0,0,0,0,0,0,0};
        for (int u = 0; u < 128; ++u) {
          float bv = b2[u * 128 + w];
#pragma unroll
          for (int e = 0; e < 8; ++e) ta[e] = fmaf(s1s[e * 128 + u], bv, ta[e]);
        }
        for (int u = 0; u < 64; ++u) {
          float bv = b2[N1 + N2 + N3 + u * 128 + w];
#pragma unroll
          for (int e = 0; e < 8; ++e) td[e] = fmaf(dts[e * 64 + u], bv, td[e]);
        }
        const float bw = bias[w];
#pragma unroll
        for (int e = 0; e < 8; ++e)
          out[(size_t)(e0 + e) * 320 + c] = fmaf(s2s[e], ta[e], ISQ3 * td[e]) + bw;
      } else {
        const int q = c - 128, w = q / 3, i = q % 3;
        float tb[8] = {0,0,0,0,0,0,0,0}, tc[8] = {0,0,0,0,0,0,0,0};
        for (int u = 0; u < 128; ++u) {
          float bv = b2[N1 + u * 64 + w];
#pragma unroll
          for (int e = 0; e < 8; ++e) tb[e] = fmaf(s1s[e * 128 + u], bv, tb[e]);
        }
        for (int u = 0; u < 64; ++u) {
          float bv = b2[N1 + N2 + u * 64 + w];
#pragma unroll
          for (int e = 0; e < 8; ++e) tc[e] = fmaf(v1s[(e * 64 + u) * 3 + i], bv, tc[e]);
        }
#pragma unroll
        for (int e = 0; e < 8; ++e)
          out[(size_t)(e0 + e) * 320 + c] = tb[e] * v2s[e * 3 + i] + tc[e] * s2s[e];
      }
    }
  } else if (bid < 1664) {
    const int g = (bid - 512) * 256 + tid;
    const int lane = g & 63;
    const int nth = g >> 6;
    const int kh = nth & 1, nt = nth >> 1;
    const int n = nt * 16 + (lane & 15);
    const int k0 = kh * 32 + (lane >> 4) * 8;
    short8 v;
#pragma unroll
    for (int q = 0; q < 8; ++q) v[q] = (short)f2bf(W2[(size_t)(k0 + q) * WN + n]);
    *(short8*)(Bp + (size_t)g * 8) = v;
  } else if (bid < 2688) {
    float* h0s = shm;
    const int r = tid >> 6, jj = tid & 63;
    const int e = (bid - 1664) * 4 + r;
    float a = b0[jj];
#pragma unroll
    for (int i = 0; i < 16; ++i) a = fmaf(wgt[e * 16 + i], W0[i * 64 + jj], a);
    h0s[r * 64 + jj] = fmaxf(a, 0.f);
    __syncthreads();
    float a1 = b1[jj];
#pragma unroll
    for (int i = 0; i < 64; ++i) a1 = fmaf(h0s[r * 64 + i], W1[i * 64 + jj], a1);
    H[e * 64 + jj] = fmaxf(a1, 0.f);
  } else {
    float* d1s = shm;            // [32][321]
    float* d2s = shm + 10272;    // [32][4]
    const int e0 = (bid - 2688) * 32;
    for (int x = tid; x < 32 * 320; x += 256) {
      int e = x / 320, c = x % 320;
      d1s[e * 321 + c] = d1[(size_t)(e0 + e) * 320 + c];
    }
    if (tid < 128) d2s[tid] = d2[(size_t)e0 * 4 + tid];
    __syncthreads();
    const int e = tid & 31;
    const float s2 = d2s[e * 4 + 0];
    const float w1 = d2s[e * 4 + 1], w2 = d2s[e * 4 + 2], w3 = d2s[e * 4 + 3];
    for (int row = (tid >> 5); row < 516; row += 8) {
      float v; float* dst;
      if (row < 128)      { v = d1s[e * 321 + row] * s2;            dst = sAg + (size_t)row * 4096; }
      else if (row < 256) { v = d1s[e * 321 + (row - 128)];         dst = sBg + (size_t)(row - 128) * 4096; }
      else if (row < 320) { int u = row - 256;
        v = ISQ3 * (d1s[e * 321 + 128 + 3 * u] * w1 + d1s[e * 321 + 129 + 3 * u] * w2 +
                    d1s[e * 321 + 130 + 3 * u] * w3);               dst = sDg + (size_t)u * 4096; }
      else if (row < 512) { v = d1s[e * 321 + 128 + (row - 320)] * s2; dst = sCg + (size_t)(row - 320) * 4096; }
      else                { v = d2s[e * 4 + (row - 512)];           dst = d2T + (size_t)(row - 512) * 4096; }
      dst[e0 + e] = v;
    }
  }
}

// ---------------- main: pre-scaled fragments, MFMA-chained accumulation ----------------
// 256 blocks = 128 e-tiles(32) x 2 nt-halves; 8 waves (512 thr) split u; no barriers in loops.

#define ADBODY(F0,F1,F2,F3,F4,F5,F6,F7,S0,S1) do {                             \
    short8 g00,g01,g10,g11;                                                    \
    SYNTH(S0, hf0, g00, g01); SYNTH(S1, hf1, g10, g11);                        \
    __builtin_amdgcn_s_setprio(1);                                             \
    a00 = MFMA(F0,g00,a00); a00 = MFMA(F1,g01,a00);                            \
    a01 = MFMA(F0,g10,a01); a01 = MFMA(F1,g11,a01);                            \
    a10 = MFMA(F2,g00,a10); a10 = MFMA(F3,g01,a10);                            \
    a11 = MFMA(F2,g10,a11); a11 = MFMA(F3,g11,a11);                            \
    a20 = MFMA(F4,g00,a20); a20 = MFMA(F5,g01,a20);                            \
    a21 = MFMA(F4,g10,a21); a21 = MFMA(F5,g11,a21);                            \
    a30 = MFMA(F6,g00,a30); a30 = MFMA(F7,g01,a30);                            \
    a31 = MFMA(F6,g10,a31); a31 = MFMA(F7,g11,a31);                            \
    __builtin_amdgcn_s_setprio(0);                                             \
  } while (0)

#define BBODY(F0,F1,F2,F3,S0,S1) do {                                          \
    short8 g00,g01,g10,g11;                                                    \
    SYNTH(S0, hf0, g00, g01); SYNTH(S1, hf1, g10, g11);                        \
    __builtin_amdgcn_s_setprio(1);                                             \
    b00 = MFMA(F0,g00,b00); b00 = MFMA(F1,g01,b00);                            \
    b01 = MFMA(F0,g10,b01); b01 = MFMA(F1,g11,b01);                            \
    b10 = MFMA(F2,g00,b10); b10 = MFMA(F3,g01,b10);                            \
    b11 = MFMA(F2,g10,b11); b11 = MFMA(F3,g11,b11);                            \
    __builtin_amdgcn_s_setprio(0);                                             \
  } while (0)

#define CBODY(F0,F1,F2,F3,S00,S01,S10,S11,S20,S21) do {                        \
    __builtin_amdgcn_s_setprio(1);                                             \
    f32x4 t00 = Zv; t00 = MFMA(F0,hb00,t00); t00 = MFMA(F1,hb01,t00);          \
    f32x4 t01 = Zv; t01 = MFMA(F0,hb10,t01); t01 = MFMA(F1,hb11,t01);          \
    f32x4 t10 = Zv; t10 = MFMA(F2,hb00,t10); t10 = MFMA(F3,hb01,t10);          \
    f32x4 t11 = Zv; t11 = MFMA(F2,hb10,t11); t11 = MFMA(F3,hb11,t11);          \
    __builtin_amdgcn_s_setprio(0);                                             \
    c000 += S00*t00; c001 += S01*t01; c010 += S00*t10; c011 += S01*t11;        \
    c100 += S10*t00; c101 += S11*t01; c110 += S10*t10; c111 += S11*t11;        \
    c200 += S20*t00; c201 += S21*t01; c210 += S20*t10; c211 += S21*t11;        \
  } while (0)

__global__ __launch_bounds__(512, 2)
void k_main(const float* __restrict__ sAg, const float* __restrict__ sBg,
            const float* __restrict__ sDg, const float* __restrict__ sCg,
            const float* __restrict__ d2T, const float* __restrict__ H,
            const unsigned short* __restrict__ Bp, float* __restrict__ out) {
  __shared__ __align__(16) float buf[4 * 32 * 136];   // 69.6 KB, reused AD then BC
  const int tid = threadIdx.x;
  const int wid = tid >> 6, lane = tid & 63;
  const int nl = lane & 15, grp = lane >> 4;
  const int h = (blockIdx.x >> 2) & 1;                       // XCD 0-3 -> half 0, 4-7 -> half 1
  const int tile = (blockIdx.x >> 3) * 4 + (blockIdx.x & 3);
  const int e0 = tile * 32;
  const short8* Bp8 = (const short8*)Bp;
  const f32x4 Zv = {0.f, 0.f, 0.f, 0.f};

  // H rows (f32) in registers: hf[eF][k], k = kh*8 + q
  float hf0[16], hf1[16];
  {
    const float* hp0 = H + (size_t)(e0 + nl) * 64 + grp * 8;
    const float* hp1 = H + (size_t)(e0 + 16 + nl) * 64 + grp * 8;
    f32x4 x0 = *(const f32x4*)(hp0),      x1 = *(const f32x4*)(hp0 + 4);
    f32x4 x2 = *(const f32x4*)(hp0 + 32), x3 = *(const f32x4*)(hp0 + 36);
    f32x4 y0 = *(const f32x4*)(hp1),      y1 = *(const f32x4*)(hp1 + 4);
    f32x4 y2 = *(const f32x4*)(hp1 + 32), y3 = *(const f32x4*)(hp1 + 36);
#pragma unroll
    for (int q = 0; q < 4; ++q) {
      hf0[q] = x0[q]; hf0[4+q] = x1[q]; hf0[8+q] = x2[q]; hf0[12+q] = x3[q];
      hf1[q] = y0[q]; hf1[4+q] = y1[q]; hf1[8+q] = y2[q]; hf1[12+q] = y3[q];
    }
  }

  f32x4 a00=Zv,a01=Zv,a10=Zv,a11=Zv,a20=Zv,a21=Zv,a30=Zv,a31=Zv;

  // ---- phase A: u = wid*16 .. +16, nt = u*8 + 4h + j ----
  {
    const int u0 = wid * 16;
    const short8* pe = Bp8 + (size_t)(u0 * 8 + 4 * h) * 128 + lane;
    const short8* po = pe + 1024;
    const float* se = sAg + (size_t)u0 * 4096 + e0 + nl;
    const float* so = se + 4096;
    short8 Ea0=pe[0],Ea1=pe[64],Ea2=pe[128],Ea3=pe[192],Ea4=pe[256],Ea5=pe[320],Ea6=pe[384],Ea7=pe[448];
    short8 Oa0=po[0],Oa1=po[64],Oa2=po[128],Oa3=po[192],Oa4=po[256],Oa5=po[320],Oa6=po[384],Oa7=po[448];
    float sE0=se[0], sE1=se[16], sO0=so[0], sO1=so[16];
#pragma unroll 2
    for (int t = 0; t < 8; ++t) {
      ADBODY(Ea0,Ea1,Ea2,Ea3,Ea4,Ea5,Ea6,Ea7, sE0,sE1);
      pe += 2048; se += 8192;
      Ea0=pe[0];Ea1=pe[64];Ea2=pe[128];Ea3=pe[192];Ea4=pe[256];Ea5=pe[320];Ea6=pe[384];Ea7=pe[448];
      sE0=se[0]; sE1=se[16];
      ADBODY(Oa0,Oa1,Oa2,Oa3,Oa4,Oa5,Oa6,Oa7, sO0,sO1);
      po += 2048; so += 8192;
      Oa0=po[0];Oa1=po[64];Oa2=po[128];Oa3=po[192];Oa4=po[256];Oa5=po[320];Oa6=po[384];Oa7=po[448];
      sO0=so[0]; sO1=so[16];
    }
  }

  f32x4 b00=Zv,b01=Zv,b10=Zv,b11=Zv;

  // ---- phase B: u = wid*16 .. +16, nt = 1024 + u*4 + 2h + j ----
  {
    const int u0 = wid * 16;
    const short8* pe = Bp8 + (size_t)(1024 + u0 * 4 + 2 * h) * 128 + lane;
    const short8* po = pe + 512;
    const float* se = sBg + (size_t)u0 * 4096 + e0 + nl;
    const float* so = se + 4096;
    short8 Ea0=pe[0],Ea1=pe[64],Ea2=pe[128],Ea3=pe[192];
    short8 Oa0=po[0],Oa1=po[64],Oa2=po[128],Oa3=po[192];
    float sE0=se[0], sE1=se[16], sO0=so[0], sO1=so[16];
#pragma unroll 2
    for (int t = 0; t < 8; ++t) {
      BBODY(Ea0,Ea1,Ea2,Ea3, sE0,sE1);
      pe += 1024; se += 8192;
      Ea0=pe[0];Ea1=pe[64];Ea2=pe[128];Ea3=pe[192];
      sE0=se[0]; sE1=se[16];
      BBODY(Oa0,Oa1,Oa2,Oa3, sO0,sO1);
      po += 1024; so += 8192;
      Oa0=po[0];Oa1=po[64];Oa2=po[128];Oa3=po[192];
      sO0=so[0]; sO1=so[16];
    }
  }

  // ---- phase D: u = wid*8 .. +8, nt = 1792 + u*8 + 4h + j (same acc as A) ----
  {
    const int u0 = wid * 8;
    const short8* pe = Bp8 + (size_t)(1792 + u0 * 8 + 4 * h) * 128 + lane;
    const short8* po = pe + 1024;
    const float* se = sDg + (size_t)u0 * 4096 + e0 + nl;
    const float* so = se + 4096;
    short8 Ea0=pe[0],Ea1=pe[64],Ea2=pe[128],Ea3=pe[192],Ea4=pe[256],Ea5=pe[320],Ea6=pe[384],Ea7=pe[448];
    short8 Oa0=po[0],Oa1=po[64],Oa2=po[128],Oa3=po[192],Oa4=po[256],Oa5=po[320],Oa6=po[384],Oa7=po[448];
    float sE0=se[0], sE1=se[16], sO0=so[0], sO1=so[16];
#pragma unroll 2
    for (int t = 0; t < 4; ++t) {
      ADBODY(Ea0,Ea1,Ea2,Ea3,Ea4,Ea5,Ea6,Ea7, sE0,sE1);
      pe += 2048; se += 8192;
      Ea0=pe[0];Ea1=pe[64];Ea2=pe[128];Ea3=pe[192];Ea4=pe[256];Ea5=pe[320];Ea6=pe[384];Ea7=pe[448];
      sE0=se[0]; sE1=se[16];
      ADBODY(Oa0,Oa1,Oa2,Oa3,Oa4,Oa5,Oa6,Oa7, sO0,sO1);
      po += 2048; so += 8192;
      Oa0=po[0];Oa1=po[64];Oa2=po[128];Oa3=po[192];Oa4=po[256];Oa5=po[320];Oa6=po[384];Oa7=po[448];
      sO0=so[0]; sO1=so[16];
    }
  }

  // ---- phase C: u = wid*8 .. +8, nt = 1536 + u*4 + 2h + j (t-temp + 3 scales) ----
  short8 hb00, hb01, hb10, hb11;
  SYNTH(1.0f, hf0, hb00, hb01);
  SYNTH(1.0f, hf1, hb10, hb11);
  f32x4 c000=Zv,c001=Zv,c010=Zv,c011=Zv,c100=Zv,c101=Zv,c110=Zv,c111=Zv,c200=Zv,c201=Zv,c210=Zv,c211=Zv;
  {
    const int u0 = wid * 8;
    const short8* pe = Bp8 + (size_t)(1536 + u0 * 4 + 2 * h) * 128 + lane;
    const short8* po = pe + 512;
    const float* sc0e = sCg + (size_t)(3 * u0) * 4096 + e0 + nl;
    const float* sc1e = sc0e + 4096;
    const float* sc2e = sc0e + 8192;
    const float* sc0o = sc0e + 12288;
    const float* sc1o = sc0e + 16384;
    const float* sc2o = sc0e + 20480;
    short8 Ea0=pe[0],Ea1=pe[64],Ea2=pe[128],Ea3=pe[192];
    short8 Oa0=po[0],Oa1=po[64],Oa2=po[128],Oa3=po[192];
    float sE00=sc0e[0],sE01=sc0e[16],sE10=sc1e[0],sE11=sc1e[16],sE20=sc2e[0],sE21=sc2e[16];
    float sO00=sc0o[0],sO01=sc0o[16],sO10=sc1o[0],sO11=sc1o[16],sO20=sc2o[0],sO21=sc2o[16];
#pragma unroll 2
    for (int t = 0; t < 4; ++t) {
      CBODY(Ea0,Ea1,Ea2,Ea3, sE00,sE01,sE10,sE11,sE20,sE21);
      pe += 1024; sc0e += 24576; sc1e += 24576; sc2e += 24576;
      Ea0=pe[0];Ea1=pe[64];Ea2=pe[128];Ea3=pe[192];
      sE00=sc0e[0];sE01=sc0e[16];sE10=sc1e[0];sE11=sc1e[16];sE20=sc2e[0];sE21=sc2e[16];
      CBODY(Oa0,Oa1,Oa2,Oa3, sO00,sO01,sO10,sO11,sO20,sO21);
      po += 1024; sc0o += 24576; sc1o += 24576; sc2o += 24576;
      Oa0=po[0];Oa1=po[64];Oa2=po[128];Oa3=po[192];
      sO00=sc0o[0];sO01=sc0o[16];sO10=sc1o[0];sO11=sc1o[16];sO20=sc2o[0];sO21=sc2o[16];
    }
  }

  // ===== epilogue: pairwise 8->4 wave reduce in LDS, then 4-way sum, += out =====
  // AD: buf as [4][32][65]
  {
    f32x4 av[8] = {a00,a01,a10,a11,a20,a21,a30,a31};
    const int ew = (wid & 3) * 2080;
    if (wid >= 4) {
#pragma unroll
      for (int j = 0; j < 4; ++j)
#pragma unroll
        for (int eF = 0; eF < 2; ++eF) {
          float* p = &buf[ew + (eF * 16 + nl) * 65 + j * 16 + grp * 4];
#pragma unroll
          for (int r = 0; r < 4; ++r) p[r] = av[j * 2 + eF][r];
        }
    }
    __syncthreads();
    if (wid < 4) {
#pragma unroll
      for (int j = 0; j < 4; ++j)
#pragma unroll
        for (int eF = 0; eF < 2; ++eF) {
          float* p = &buf[ew + (eF * 16 + nl) * 65 + j * 16 + grp * 4];
#pragma unroll
          for (int r = 0; r < 4; ++r) p[r] += av[j * 2 + eF][r];
        }
    }
    __syncthreads();
#pragma unroll
    for (int it = 0; it < 4; ++it) {
      const int p = tid + it * 512;
      const int e = p >> 6, s = p & 63;
      float v = buf[e * 65 + s] + buf[2080 + e * 65 + s] +
                buf[4160 + e * 65 + s] + buf[6240 + e * 65 + s];
      out[(size_t)(e0 + e) * 320 + 64 * h + s] += v;
    }
    __syncthreads();
  }
  // BC: buf as [4][32][136], slots {tb, tc0, tc1, tc2} per (e, w1)
  {
    f32x4 bv[4] = {b00,b01,b10,b11};
    f32x4 cv[12] = {c000,c001,c010,c011,c100,c101,c110,c111,c200,c201,c210,c211};
    const int ew = (wid & 3) * 4352;
    if (wid >= 4) {
#pragma unroll
      for (int j = 0; j < 2; ++j)
#pragma unroll
        for (int eF = 0; eF < 2; ++eF)
#pragma unroll
          for (int r = 0; r < 4; ++r) {
            const int w1 = j * 16 + grp * 4 + r;
            f32x4 st = {bv[j*2+eF][r], cv[j*2+eF][r], cv[4 + j*2+eF][r], cv[8 + j*2+eF][r]};
            *(f32x4*)&buf[ew + (eF * 16 + nl) * 136 + w1 * 4] = st;
          }
    }
    __syncthreads();
    if (wid < 4) {
#pragma unroll
      for (int j = 0; j < 2; ++j)
#pragma unroll
        for (int eF = 0; eF < 2; ++eF)
#pragma unroll
          for (int r = 0; r < 4; ++r) {
            const int w1 = j * 16 + grp * 4 + r;
            f32x4* p = (f32x4*)&buf[ew + (eF * 16 + nl) * 136 + w1 * 4];
            f32x4 st = {bv[j*2+eF][r], cv[j*2+eF][r], cv[4 + j*2+eF][r], cv[8 + j*2+eF][r]};
            *p = *p + st;
          }
    }
    __syncthreads();
#pragma unroll
    for (int it = 0; it < 2; ++it) {
      const int p = tid + it * 512;
      const int e = p >> 5, w1 = p & 31;
      f32x4 v = *(const f32x4*)&buf[e * 136 + w1 * 4];
      v += *(const f32x4*)&buf[4352 + e * 136 + w1 * 4];
      v += *(const f32x4*)&buf[8704 + e * 136 + w1 * 4];
      v += *(const f32x4*)&buf[13056 + e * 136 + w1 * 4];
      const float v20 = d2T[4096 + e0 + e], v21 = d2T[8192 + e0 + e], v22 = d2T[12288 + e0 + e];
      float* op = out + (size_t)(e0 + e) * 320 + 128 + (size_t)(32 * h + w1) * 3;
      op[0] += v[0] * v20 + v[1];
      op[1] += v[0] * v21 + v[2];
      op[2] += v[0] * v22 + v[3];
    }
  }
}

extern "C" void kernel_launch(void* const* d_in, const int* in_sizes, int n_in,
                              void* d_out, int out_size, void* d_ws, size_t ws_size,
                              hipStream_t stream) {
  const float* d1   = (const float*)d_in[0];
  const float* d2   = (const float*)d_in[1];
  const float* wgt  = (const float*)d_in[2];
  const float* W0   = (const float*)d_in[3];
  const float* b0   = (const float*)d_in[4];
  const float* W1   = (const float*)d_in[5];
  const float* b1   = (const float*)d_in[6];
  const float* W2   = (const float*)d_in[7];
  const float* b2   = (const float*)d_in[8];
  const float* bias = (const float*)d_in[9];
  float* out = (float*)d_out;

  char* ws = (char*)d_ws;
  float* H           = (float*)(ws);                         // 1 MiB
  unsigned short* Bp = (unsigned short*)(ws + (1u << 20));   // 4.72 MB
  float* sAg         = (float*)(ws + (6u << 20));            // 2 MB  [128][4096] s1*s2
  float* sBg         = (float*)(ws + (8u << 20));            // 2 MB  [128][4096] s1
  float* sDg         = (float*)(ws + (10u << 20));           // 1 MB  [64][4096]  ISQ3*dot12
  float* sCg         = (float*)(ws + (11u << 20));           // 3 MB  [192][4096] v1_i*s2
  float* d2T         = (float*)(ws + (14u << 20));           // 64 KB [4][4096]

  k_prep<<<2816, 256, 0, stream>>>(wgt, W0, b0, W1, b1, W2, b2, bias, d1, d2,
                                   H, Bp, sAg, sBg, sDg, sCg, d2T, out);
  k_main<<<256, 512, 0, stream>>>(sAg, sBg, sDg, sCg, d2T, H, Bp, out);
}